// Round 2
// baseline (3308.397 us; speedup 1.0000x reference)
//
#include <hip/hip_runtime.h>
#include <math.h>

#define T_  6
#define N_  50000
#define NH_ 128
#define H_  4
#define D_  32
#define R_  2
#define E_  800000
#define CH_ 12500           // temporal chunk (nodes); 4 chunks
#define SEMW_BLOCKS ((2*N_ + 63)/64)   // 1563

// ---------------------------------------------------------------- CSR build
__global__ void hist_kernel(const int* __restrict__ dst, int* __restrict__ counts) {
    int j = blockIdx.x * blockDim.x + threadIdx.x;
    if (j < R_ * E_) atomicAdd(&counts[(j / E_) * N_ + dst[j]], 1);
}

__global__ __launch_bounds__(1024) void scan_kernel(const int* __restrict__ counts,
                                                    int* __restrict__ offsets,
                                                    int* __restrict__ cursor) {
    int r = blockIdx.x;
    __shared__ int sm[1024];
    __shared__ int carry;
    if (threadIdx.x == 0) carry = 0;
    __syncthreads();
    for (int base = 0; base < N_; base += 1024) {
        int i = base + threadIdx.x;
        int v = (i < N_) ? counts[r * N_ + i] : 0;
        sm[threadIdx.x] = v;
        __syncthreads();
        for (int off = 1; off < 1024; off <<= 1) {
            int t = 0;
            if (threadIdx.x >= off) t = sm[threadIdx.x - off];
            __syncthreads();
            sm[threadIdx.x] += t;
            __syncthreads();
        }
        int incl = sm[threadIdx.x];
        int run = carry;
        int excl = run + incl - v;
        if (i < N_) { offsets[r * (N_ + 1) + i] = excl; cursor[r * N_ + i] = excl; }
        __syncthreads();
        if (threadIdx.x == 1023) carry = run + incl;
        __syncthreads();
    }
    if (threadIdx.x == 0) offsets[r * (N_ + 1) + N_] = carry;
}

__global__ void scatter_kernel(const int* __restrict__ src, const int* __restrict__ dst,
                               int* __restrict__ cursor, int* __restrict__ srcs_sorted) {
    int j = blockIdx.x * blockDim.x + threadIdx.x;
    if (j < R_ * E_) {
        int r = j / E_;
        int pos = atomicAdd(&cursor[r * N_ + dst[j]], 1);
        srcs_sorted[(size_t)r * E_ + pos] = src[j];
    }
}

// ---------------------------------------------------------------- small precomputes
__global__ void pe_kernel(float* __restrict__ pe) {
    int c = threadIdx.x;           // 0..127
    int k = c & ~1;
    double div = exp((double)k * (-log(100000.0) / 128.0));
    for (int t = 0; t < T_; t++) {
        double pos = (double)(t + 1);
        double v = (c & 1) ? cos(pos * div) : sin(pos * div);
        pe[t * NH_ + c] = (float)v;
    }
}

// which==0: Wu[f][e] = sum_d kw[f][d]*qw[e][d]   (so u = hh @ Wu gives sc_ts = q_t . k_s)
// which==1: Wvf[e][c] = sum_d vw[e][d]*fc_w[d][c] (so wv = hh @ Wvf gives (v@fc_w))
__global__ void build_small_kernel(const float* __restrict__ qw, const float* __restrict__ kw,
                                   const float* __restrict__ vw, const float* __restrict__ fcw,
                                   float* __restrict__ Wu, float* __restrict__ Wvf) {
    int row = blockIdx.x, c = threadIdx.x, which = blockIdx.y;
    float s = 0.f;
    if (which == 0) {
        for (int d = 0; d < NH_; d++) s += kw[row * NH_ + d] * qw[c * NH_ + d];
        Wu[row * NH_ + c] = s;
    } else {
        for (int d = 0; d < NH_; d++) s += vw[row * NH_ + d] * fcw[d * NH_ + c];
        Wvf[row * NH_ + c] = s;
    }
}

// ---------------------------------------------------------------- generic GEMM  C[M,128] = epi(A[M,128] @ W)
struct GemmArgs {
    const float* A;
    const float* W0; const float* W1; const float* W2; const float* W3;
    const float* b0; const float* b1; const float* b2; const float* b3;
    float* C0; float* C1; float* C2; float* C3;
    const float* pe;
    long row0;   // used ONLY for mode-1 addressing and the pe[t] epilogue
    int  M;
    int  mode;   // 0: A row = local row (A already points at chunk); 1: global row g=row0+i -> n=g/6,t=g%6, A row = t*N_+n
    int  epi;    // 0: none; 1: +bias; 2: +bias + pe[t]
};

#define FMA4(r, av) \
    acc[r][0] = fmaf(av, w.x, acc[r][0]); \
    acc[r][1] = fmaf(av, w.y, acc[r][1]); \
    acc[r][2] = fmaf(av, w.z, acc[r][2]); \
    acc[r][3] = fmaf(av, w.w, acc[r][3]);

__global__ __launch_bounds__(256) void gemm_kernel(GemmArgs g) {
    __shared__ float Ws[32 * 128];
    __shared__ float As[32 * 68];
    int y = blockIdx.y;
    const float* W    = (y == 0) ? g.W0 : (y == 1) ? g.W1 : (y == 2) ? g.W2 : g.W3;
    const float* bias = (y == 0) ? g.b0 : (y == 1) ? g.b1 : (y == 2) ? g.b2 : g.b3;
    float* C          = (y == 0) ? g.C0 : (y == 1) ? g.C1 : (y == 2) ? g.C2 : g.C3;

    int tid = threadIdx.x;
    int brow0 = blockIdx.x * 64;
    int lrow = tid >> 2, q = tid & 3;
    int grow = brow0 + lrow;
    bool valid = grow < g.M;
    const float* Arow = nullptr;
    if (valid) {
        long ar;
        if (g.mode == 0) ar = grow;                     // A already chunk-offset
        else { long gg = g.row0 + grow; long n = gg / 6, t = gg - n * 6; ar = t * (long)N_ + n; }
        Arow = g.A + ar * (long)NH_;
    }
    int tx = tid & 31, ty = tid >> 5;
    float acc[8][4];
#pragma unroll
    for (int i = 0; i < 8; i++)
#pragma unroll
        for (int j = 0; j < 4; j++) acc[i][j] = 0.f;

    const float4* Wg4 = (const float4*)W;
    float4* Ws4 = (float4*)Ws;
    const float4* As4 = (const float4*)As;

    for (int kt = 0; kt < 4; kt++) {
        __syncthreads();
#pragma unroll
        for (int i = 0; i < 4; i++) Ws4[tid + i * 256] = Wg4[kt * 1024 + tid + i * 256];
#pragma unroll
        for (int j = 0; j < 2; j++) {
            int c4 = q + 4 * j;                         // 0..7
            float4 v = valid ? *(const float4*)(Arow + kt * 32 + c4 * 4)
                             : make_float4(0.f, 0.f, 0.f, 0.f);
            int kl = c4 * 4;
            As[(kl + 0) * 68 + lrow] = v.x;
            As[(kl + 1) * 68 + lrow] = v.y;
            As[(kl + 2) * 68 + lrow] = v.z;
            As[(kl + 3) * 68 + lrow] = v.w;
        }
        __syncthreads();
#pragma unroll
        for (int k = 0; k < 32; k++) {
            float4 w  = Ws4[k * 32 + tx];
            float4 A0 = As4[k * 17 + ty * 2];
            float4 A1 = As4[k * 17 + ty * 2 + 1];
            FMA4(0, A0.x) FMA4(1, A0.y) FMA4(2, A0.z) FMA4(3, A0.w)
            FMA4(4, A1.x) FMA4(5, A1.y) FMA4(6, A1.z) FMA4(7, A1.w)
        }
    }
#pragma unroll
    for (int rr = 0; rr < 8; rr++) {
        int row = ty * 8 + rr;
        int gr = brow0 + row;
        if (gr >= g.M) continue;
        float4 o = make_float4(acc[rr][0], acc[rr][1], acc[rr][2], acc[rr][3]);
        int c = tx * 4;
        if (g.epi >= 1) { o.x += bias[c]; o.y += bias[c+1]; o.z += bias[c+2]; o.w += bias[c+3]; }
        if (g.epi == 2) {
            long t = (g.row0 + gr) % 6;
            const float* p = g.pe + t * NH_ + c;
            o.x += p[0]; o.y += p[1]; o.z += p[2]; o.w += p[3];
        }
        *(float4*)(C + (size_t)gr * NH_ + c) = o;
    }
}

// ---------------------------------------------------------------- semantic w = tanh(h@W1+b1)@w2, block-partial sums per relation parity
__global__ __launch_bounds__(256) void semw_kernel(const float* __restrict__ A,
                                                   const float* __restrict__ W,
                                                   const float* __restrict__ b1,
                                                   const float* __restrict__ w2,
                                                   float* __restrict__ partials, int M) {
    __shared__ float Ws[32 * 128];
    __shared__ float As[32 * 68];
    __shared__ float bs[2];
    int tid = threadIdx.x;
    int brow0 = blockIdx.x * 64;
    int lrow = tid >> 2, q = tid & 3;
    int grow = brow0 + lrow;
    bool valid = grow < M;
    const float* Arow = valid ? (A + (size_t)grow * NH_) : nullptr;
    int tx = tid & 31, ty = tid >> 5;
    float acc[8][4];
#pragma unroll
    for (int i = 0; i < 8; i++)
#pragma unroll
        for (int j = 0; j < 4; j++) acc[i][j] = 0.f;

    const float4* Wg4 = (const float4*)W;
    float4* Ws4 = (float4*)Ws;
    const float4* As4 = (const float4*)As;
    for (int kt = 0; kt < 4; kt++) {
        __syncthreads();
#pragma unroll
        for (int i = 0; i < 4; i++) Ws4[tid + i * 256] = Wg4[kt * 1024 + tid + i * 256];
#pragma unroll
        for (int j = 0; j < 2; j++) {
            int c4 = q + 4 * j;
            float4 v = valid ? *(const float4*)(Arow + kt * 32 + c4 * 4)
                             : make_float4(0.f, 0.f, 0.f, 0.f);
            int kl = c4 * 4;
            As[(kl + 0) * 68 + lrow] = v.x;
            As[(kl + 1) * 68 + lrow] = v.y;
            As[(kl + 2) * 68 + lrow] = v.z;
            As[(kl + 3) * 68 + lrow] = v.w;
        }
        __syncthreads();
#pragma unroll
        for (int k = 0; k < 32; k++) {
            float4 w  = Ws4[k * 32 + tx];
            float4 A0 = As4[k * 17 + ty * 2];
            float4 A1 = As4[k * 17 + ty * 2 + 1];
            FMA4(0, A0.x) FMA4(1, A0.y) FMA4(2, A0.z) FMA4(3, A0.w)
            FMA4(4, A1.x) FMA4(5, A1.y) FMA4(6, A1.z) FMA4(7, A1.w)
        }
    }
    if (tid < 2) bs[tid] = 0.f;
    __syncthreads();
    int c0 = tx * 4;
    float rsum[8];
#pragma unroll
    for (int rr = 0; rr < 8; rr++) {
        float s = 0.f;
#pragma unroll
        for (int i = 0; i < 4; i++) {
            int c = c0 + i;
            s += tanhf(acc[rr][i] + b1[c]) * w2[c];
        }
#pragma unroll
        for (int mask = 1; mask <= 16; mask <<= 1) s += __shfl_xor(s, mask);
        rsum[rr] = s;
    }
    if (tx == 0) {
#pragma unroll
        for (int rr = 0; rr < 8; rr++) {
            int gr = brow0 + ty * 8 + rr;
            if (gr < M) atomicAdd(&bs[gr & 1], rsum[rr]);
        }
    }
    __syncthreads();
    if (tid < 2) partials[blockIdx.x * 2 + tid] = bs[tid];
}

__global__ __launch_bounds__(512) void beta_kernel(const float* __restrict__ partials, int nb,
                                                   float* __restrict__ beta) {
    float s0 = 0.f, s1 = 0.f;
    for (int i = threadIdx.x; i < nb; i += 512) { s0 += partials[i * 2]; s1 += partials[i * 2 + 1]; }
#pragma unroll
    for (int mask = 1; mask <= 32; mask <<= 1) { s0 += __shfl_xor(s0, mask); s1 += __shfl_xor(s1, mask); }
    __shared__ float w0[8], w1[8];
    int w = threadIdx.x >> 6;
    if ((threadIdx.x & 63) == 0) { w0[w] = s0; w1[w] = s1; }
    __syncthreads();
    if (threadIdx.x == 0) {
        float t0 = 0.f, t1 = 0.f;
        for (int i = 0; i < 8; i++) { t0 += w0[i]; t1 += w1[i]; }
        float m0 = t0 / (float)N_, m1 = t1 / (float)N_;
        float mx = fmaxf(m0, m1);
        float e0 = __expf(m0 - mx), e1 = __expf(m1 - mx);
        float inv = 1.f / (e0 + e1);
        beta[0] = e0 * inv; beta[1] = e1 * inv;
    }
}

// ---------------------------------------------------------------- GAT edge aggregation: one wave per dst node
__global__ __launch_bounds__(256) void gat_edge_kernel(const float* __restrict__ fsb,
                                                       const float* __restrict__ fdb,
                                                       const int* __restrict__ offsets,
                                                       const int* __restrict__ srcs_sorted,
                                                       const float* __restrict__ gat_attn,
                                                       const float* __restrict__ gat_bias,
                                                       float* __restrict__ hout) {
    int r = blockIdx.y;
    const float* fs = fsb + (size_t)r * N_ * NH_;
    const float* fd = fdb + (size_t)r * N_ * NH_;
    const int* offs = offsets + r * (N_ + 1);
    const int* srcs = srcs_sorted + (size_t)r * E_;
    int lane = threadIdx.x & 63;
    int wid = (blockIdx.x * blockDim.x + threadIdx.x) >> 6;
    int nw = (gridDim.x * blockDim.x) >> 6;
    float a0 = gat_attn[r * NH_ + lane];
    float a1 = gat_attn[r * NH_ + 64 + lane];
    float b0 = gat_bias[r * NH_ + lane];
    float b1 = gat_bias[r * NH_ + 64 + lane];
    for (int n = wid; n < N_; n += nw) {
        float fd0 = fd[(size_t)n * NH_ + lane];
        float fd1 = fd[(size_t)n * NH_ + 64 + lane];
        int e0 = offs[n], e1 = offs[n + 1];
        float m0 = -1e30f, m1 = -1e30f, s0 = 0.f, s1 = 0.f, acc0 = 0.f, acc1 = 0.f;
        float f0 = 0.f, f1 = 0.f;
        if (e0 < e1) {
            int s = srcs[e0];
            f0 = fs[(size_t)s * NH_ + lane];
            f1 = fs[(size_t)s * NH_ + 64 + lane];
        }
        for (int e = e0; e < e1; e++) {
            float nf0 = 0.f, nf1 = 0.f;
            if (e + 1 < e1) {
                int s = srcs[e + 1];
                nf0 = fs[(size_t)s * NH_ + lane];
                nf1 = fs[(size_t)s * NH_ + 64 + lane];
            }
            float v0 = f0 + fd0; v0 = (v0 > 0.f) ? v0 : 0.2f * v0; v0 *= a0;
            float v1 = f1 + fd1; v1 = (v1 > 0.f) ? v1 : 0.2f * v1; v1 *= a1;
#pragma unroll
            for (int mask = 1; mask <= 16; mask <<= 1) {
                v0 += __shfl_xor(v0, mask);
                v1 += __shfl_xor(v1, mask);
            }
            float nm0 = fmaxf(m0, v0), nm1 = fmaxf(m1, v1);
            float sc0 = __expf(m0 - nm0), sc1 = __expf(m1 - nm1);
            float p0 = __expf(v0 - nm0), p1 = __expf(v1 - nm1);
            s0 = s0 * sc0 + p0;       s1 = s1 * sc1 + p1;
            acc0 = acc0 * sc0 + p0 * f0;  acc1 = acc1 * sc1 + p1 * f1;
            m0 = nm0; m1 = nm1;
            f0 = nf0; f1 = nf1;
        }
        float o0 = (e1 > e0) ? acc0 / s0 : 0.f;
        float o1 = (e1 > e0) ? acc1 / s1 : 0.f;
        hout[((size_t)n * R_ + r) * NH_ + lane]      = o0 + b0;
        hout[((size_t)n * R_ + r) * NH_ + 64 + lane] = o1 + b1;
    }
}

// ---------------------------------------------------------------- hsem + relu + bias + relu -> inter[n][t][:]
__global__ void hsem_kernel(const float* __restrict__ h, const float* __restrict__ beta,
                            const float* __restrict__ h_bias, float* __restrict__ inter, int t) {
    int idx = blockIdx.x * blockDim.x + threadIdx.x;
    if (idx >= N_ * 32) return;
    int n = idx >> 5, c4 = idx & 31;
    float b0 = beta[0], b1 = beta[1];
    const float4* h4 = (const float4*)h;
    float4 x0 = h4[(size_t)n * 64 + c4];
    float4 x1 = h4[(size_t)n * 64 + 32 + c4];
    float4 hb = ((const float4*)h_bias)[c4];
    float4 z;
    z.x = fmaxf(fmaxf(b0 * x0.x + b1 * x1.x, 0.f) + hb.x, 0.f);
    z.y = fmaxf(fmaxf(b0 * x0.y + b1 * x1.y, 0.f) + hb.y, 0.f);
    z.z = fmaxf(fmaxf(b0 * x0.z + b1 * x1.z, 0.f) + hb.z, 0.f);
    z.w = fmaxf(fmaxf(b0 * x0.w + b1 * x1.w, 0.f) + hb.w, 0.f);
    ((float4*)inter)[((size_t)n * T_ + t) * 32 + c4] = z;
}

// ---------------------------------------------------------------- temporal attention + gated residual + LN (wave per node)
__global__ __launch_bounds__(256) void temporal_kernel(const float* __restrict__ hh,
                                                       const float* __restrict__ uu,
                                                       const float* __restrict__ wvv,
                                                       const float* __restrict__ rv,
                                                       const float* __restrict__ fc_b,
                                                       const float* __restrict__ res_alpha,
                                                       const float* __restrict__ ln_g,
                                                       const float* __restrict__ ln_b,
                                                       float* __restrict__ out, int n0) {
    int lane = threadIdx.x & 63;
    int wid = (blockIdx.x * blockDim.x + threadIdx.x) >> 6;   // 0..CH_-1
    int n = n0 + wid;
    size_t base = (size_t)wid * T_ * NH_;
    float2 h2[6], u2[6], w2[6], r2[6];
#pragma unroll
    for (int t = 0; t < 6; t++) {
        h2[t] = ((const float2*)(hh  + base + t * NH_))[lane];
        u2[t] = ((const float2*)(uu  + base + t * NH_))[lane];
        w2[t] = ((const float2*)(wvv + base + t * NH_))[lane];
        r2[t] = ((const float2*)(rv  + base + t * NH_))[lane];
    }
    float sc[6][6];
#pragma unroll
    for (int t = 0; t < 6; t++)
#pragma unroll
        for (int s = 0; s < 6; s++)
            sc[t][s] = h2[t].x * u2[s].x + h2[t].y * u2[s].y;
#pragma unroll
    for (int mask = 1; mask <= 32; mask <<= 1)
#pragma unroll
        for (int t = 0; t < 6; t++)
#pragma unroll
            for (int s = 0; s < 6; s++)
                sc[t][s] += __shfl_xor(sc[t][s], mask);

    float a = 1.f / (1.f + __expf(-res_alpha[0]));
    float2 fb = ((const float2*)fc_b)[lane];
    float2 lg = ((const float2*)ln_g)[lane];
    float2 lb = ((const float2*)ln_b)[lane];
#pragma unroll
    for (int t = 0; t < 6; t++) {
        float mx = sc[t][0];
#pragma unroll
        for (int s = 1; s < 6; s++) mx = fmaxf(mx, sc[t][s]);
        float p[6]; float den = 0.f;
#pragma unroll
        for (int s = 0; s < 6; s++) { p[s] = __expf(sc[t][s] - mx); den += p[s]; }
        float inv = 1.f / den;
        float ox = 0.f, oy = 0.f;
#pragma unroll
        for (int s = 0; s < 6; s++) { ox += p[s] * w2[s].x; oy += p[s] * w2[s].y; }
        ox = fmaxf(ox * inv + fb.x, 0.f);
        oy = fmaxf(oy * inv + fb.y, 0.f);
        ox = ox * a + r2[t].x * (1.f - a);
        oy = oy * a + r2[t].y * (1.f - a);
        float s1 = ox + oy, s2 = ox * ox + oy * oy;
#pragma unroll
        for (int mask = 1; mask <= 32; mask <<= 1) {
            s1 += __shfl_xor(s1, mask);
            s2 += __shfl_xor(s2, mask);
        }
        float mu = s1 * (1.f / 128.f);
        float var = s2 * (1.f / 128.f) - mu * mu;
        float rs = rsqrtf(var + 1e-5f);
        float2 o;
        o.x = (ox - mu) * rs * lg.x + lb.x;
        o.y = (oy - mu) * rs * lg.y + lb.y;
        ((float2*)(out + ((size_t)t * N_ + n) * NH_))[lane] = o;
    }
}

// ---------------------------------------------------------------- launch
extern "C" void kernel_launch(void* const* d_in, const int* in_sizes, int n_in,
                              void* d_out, int out_size, void* d_ws, size_t ws_size,
                              hipStream_t stream) {
    const float* x        = (const float*)d_in[0];
    const int*   src      = (const int*)d_in[1];
    const int*   dst      = (const int*)d_in[2];
    const float* gat_wsrc = (const float*)d_in[3];
    const float* gat_wdst = (const float*)d_in[4];
    const float* gat_attn = (const float*)d_in[5];
    const float* gat_bias = (const float*)d_in[6];
    const float* h_bias   = (const float*)d_in[7];
    const float* sem_w1   = (const float*)d_in[8];
    const float* sem_b1   = (const float*)d_in[9];
    const float* sem_w2   = (const float*)d_in[10];
    const float* proj_w   = (const float*)d_in[11];
    const float* proj_b   = (const float*)d_in[12];
    const float* qw       = (const float*)d_in[13];
    const float* kw       = (const float*)d_in[14];
    const float* vw       = (const float*)d_in[15];
    const float* fc_w     = (const float*)d_in[16];
    const float* fc_b     = (const float*)d_in[17];
    const float* res_w    = (const float*)d_in[18];
    const float* res_b    = (const float*)d_in[19];
    const float* res_alpha= (const float*)d_in[20];
    const float* ln_g     = (const float*)d_in[21];
    const float* ln_b     = (const float*)d_in[22];
    (void)in_sizes; (void)n_in; (void)out_size; (void)ws_size;

    char* ws = (char*)d_ws;
    size_t off = 0;
    auto alloc = [&](size_t bytes) -> void* {
        void* p = ws + off;
        off += (bytes + 255) & ~(size_t)255;
        return p;
    };
    int*   counts      = (int*)alloc((size_t)R_ * N_ * 4);
    int*   offsets     = (int*)alloc((size_t)R_ * (N_ + 1) * 4);
    int*   cursor      = (int*)alloc((size_t)R_ * N_ * 4);
    int*   srcs_sorted = (int*)alloc((size_t)R_ * E_ * 4);
    float* pe          = (float*)alloc(T_ * NH_ * 4);
    float* Wu          = (float*)alloc(16384 * 4);
    float* Wvf         = (float*)alloc(16384 * 4);
    float* beta        = (float*)alloc(256);
    float* partials    = (float*)alloc((size_t)SEMW_BLOCKS * 2 * 4);
    float* B           = (float*)alloc((size_t)6 * N_ * NH_ * 4);    // 153.6 MB
    float* inter       = (float*)alloc((size_t)N_ * T_ * NH_ * 4);   // 153.6 MB

    float* fsb  = B;                           // [R][N][128]
    float* fdb  = B + (size_t)2 * N_ * NH_;    // [R][N][128]
    float* hbuf = B + (size_t)4 * N_ * NH_;    // [N][R][128]
    float* hh_c = B;                                   // chunk buffers (after GAT done)
    float* u_c  = B + (size_t)1 * CH_ * T_ * NH_;
    float* wv_c = B + (size_t)2 * CH_ * T_ * NH_;
    float* rv_c = B + (size_t)3 * CH_ * T_ * NH_;

    // --- CSR build (dst is time/relation-static per relation)
    hipMemsetAsync(counts, 0, (size_t)R_ * N_ * 4, stream);
    hist_kernel<<<(R_ * E_ + 255) / 256, 256, 0, stream>>>(dst, counts);
    scan_kernel<<<R_, 1024, 0, stream>>>(counts, offsets, cursor);
    scatter_kernel<<<(R_ * E_ + 255) / 256, 256, 0, stream>>>(src, dst, cursor, srcs_sorted);
    pe_kernel<<<1, 128, 0, stream>>>(pe);
    build_small_kernel<<<dim3(128, 2), 128, 0, stream>>>(qw, kw, vw, fc_w, Wu, Wvf);

    // --- per-timestep GAT + semantic attention
    for (int t = 0; t < T_; t++) {
        const float* xt = x + (size_t)t * N_ * NH_;
        GemmArgs ga{};
        ga.A = xt; ga.mode = 0; ga.row0 = 0; ga.M = N_; ga.epi = 0;
        ga.W0 = gat_wsrc;          ga.C0 = fsb;
        ga.W1 = gat_wdst;          ga.C1 = fdb;
        ga.W2 = gat_wsrc + 16384;  ga.C2 = fsb + (size_t)N_ * NH_;
        ga.W3 = gat_wdst + 16384;  ga.C3 = fdb + (size_t)N_ * NH_;
        gemm_kernel<<<dim3((N_ + 63) / 64, 4), 256, 0, stream>>>(ga);

        gat_edge_kernel<<<dim3(2048, 2), 256, 0, stream>>>(fsb, fdb, offsets, srcs_sorted,
                                                           gat_attn, gat_bias, hbuf);

        semw_kernel<<<SEMW_BLOCKS, 256, 0, stream>>>(hbuf, sem_w1, sem_b1, sem_w2, partials, 2 * N_);
        beta_kernel<<<1, 512, 0, stream>>>(partials, SEMW_BLOCKS, beta);
        hsem_kernel<<<(N_ * 32 + 255) / 256, 256, 0, stream>>>(hbuf, beta, h_bias, inter, t);
    }

    // --- temporal attention + residual + LN (chunked over nodes)
    for (int c = 0; c < N_ / CH_; c++) {
        int n0 = c * CH_;
        int Mc = CH_ * T_;
        GemmArgs ga{};
        ga.A = inter + (size_t)n0 * T_ * NH_; ga.mode = 0; ga.row0 = (long)n0 * T_;
        ga.M = Mc; ga.epi = 2; ga.W0 = proj_w; ga.b0 = proj_b; ga.C0 = hh_c; ga.pe = pe;
        gemm_kernel<<<dim3((Mc + 63) / 64, 1), 256, 0, stream>>>(ga);

        GemmArgs gb{};
        gb.A = hh_c; gb.mode = 0; gb.row0 = 0; gb.M = Mc; gb.epi = 0;
        gb.W0 = Wu;  gb.C0 = u_c;
        gb.W1 = Wvf; gb.C1 = wv_c;
        gemm_kernel<<<dim3((Mc + 63) / 64, 2), 256, 0, stream>>>(gb);

        GemmArgs gc{};
        gc.A = x; gc.mode = 1; gc.row0 = (long)n0 * T_; gc.M = Mc; gc.epi = 1;
        gc.W0 = res_w; gc.b0 = res_b; gc.C0 = rv_c;
        gemm_kernel<<<dim3((Mc + 63) / 64, 1), 256, 0, stream>>>(gc);

        temporal_kernel<<<CH_ / 4, 256, 0, stream>>>(hh_c, u_c, wv_c, rv_c, fc_b, res_alpha,
                                                     ln_g, ln_b, (float*)d_out, n0);
    }
}

// Round 3
// 2925.516 us; speedup vs baseline: 1.1309x; 1.1309x over previous
//
#include <hip/hip_runtime.h>
#include <math.h>

#define T_  6
#define N_  50000
#define NH_ 128
#define R_  2
#define E_  800000
#define CH_ 6250            // temporal chunk (nodes); 8 chunks
#define SEMW_BLOCKS ((2*N_ + 127)/128)   // 782

typedef __attribute__((ext_vector_type(8))) short bf16x8;
typedef __attribute__((ext_vector_type(4))) float f32x4;

__device__ inline unsigned short f2b(float f) {
    union { float f; unsigned int u; } v; v.f = f;
    unsigned int u = v.u;
    unsigned int r = (u + 0x7FFFu + ((u >> 16) & 1u)) >> 16;
    return (unsigned short)r;
}
__device__ inline float b2f(unsigned short h) {
    union { unsigned int u; float f; } v; v.u = ((unsigned int)h) << 16;
    return v.f;
}

// ---------------------------------------------------------------- CSR build
__global__ void hist_kernel(const int* __restrict__ dst, int* __restrict__ counts) {
    int j = blockIdx.x * blockDim.x + threadIdx.x;
    if (j < R_ * E_) atomicAdd(&counts[(j / E_) * N_ + dst[j]], 1);
}

__global__ __launch_bounds__(1024) void scan_kernel(const int* __restrict__ counts,
                                                    int* __restrict__ offsets,
                                                    int* __restrict__ cursor) {
    int r = blockIdx.x;
    __shared__ int sm[1024];
    __shared__ int carry;
    if (threadIdx.x == 0) carry = 0;
    __syncthreads();
    for (int base = 0; base < N_; base += 1024) {
        int i = base + threadIdx.x;
        int v = (i < N_) ? counts[r * N_ + i] : 0;
        sm[threadIdx.x] = v;
        __syncthreads();
        for (int off = 1; off < 1024; off <<= 1) {
            int t = 0;
            if (threadIdx.x >= off) t = sm[threadIdx.x - off];
            __syncthreads();
            sm[threadIdx.x] += t;
            __syncthreads();
        }
        int incl = sm[threadIdx.x];
        int run = carry;
        int excl = run + incl - v;
        if (i < N_) { offsets[r * (N_ + 1) + i] = excl; cursor[r * N_ + i] = excl; }
        __syncthreads();
        if (threadIdx.x == 1023) carry = run + incl;
        __syncthreads();
    }
    if (threadIdx.x == 0) offsets[r * (N_ + 1) + N_] = carry;
}

__global__ void scatter_kernel(const int* __restrict__ src, const int* __restrict__ dst,
                               int* __restrict__ cursor, int* __restrict__ srcs_sorted) {
    int j = blockIdx.x * blockDim.x + threadIdx.x;
    if (j < R_ * E_) {
        int r = j / E_;
        int pos = atomicAdd(&cursor[r * N_ + dst[j]], 1);
        srcs_sorted[(size_t)r * E_ + pos] = src[j];
    }
}

// ---------------------------------------------------------------- small precomputes
__global__ void pe_kernel(float* __restrict__ pe) {
    int c = threadIdx.x;
    int k = c & ~1;
    double div = exp((double)k * (-log(100000.0) / 128.0));
    for (int t = 0; t < T_; t++) {
        double pos = (double)(t + 1);
        double v = (c & 1) ? cos(pos * div) : sin(pos * div);
        pe[t * NH_ + c] = (float)v;
    }
}

// x fp32 -> bf16
__global__ void cvt_x_kernel(const float* __restrict__ in, unsigned short* __restrict__ out, long n) {
    long i = ((long)blockIdx.x * blockDim.x + threadIdx.x) * 8;
    if (i >= n) return;
    float4 a = *(const float4*)(in + i);
    float4 b = *(const float4*)(in + i + 4);
    union { unsigned short s[8]; uint4 u; } o;
    o.s[0] = f2b(a.x); o.s[1] = f2b(a.y); o.s[2] = f2b(a.z); o.s[3] = f2b(a.w);
    o.s[4] = f2b(b.x); o.s[5] = f2b(b.y); o.s[6] = f2b(b.z); o.s[7] = f2b(b.w);
    *(uint4*)(out + i) = o.u;
}

// transpose+convert 128x128 weights into Wt[n][k] bf16 (y==5: hi/lo split K=256)
struct CvtArgs {
    const float* s[7];
    unsigned short* d[7];
};
__global__ void cvt_wt_kernel(CvtArgs a) {
    int y = blockIdx.y, n = blockIdx.x, k = threadIdx.x;
    float v = a.s[y][k * 128 + n];
    if (y == 5) {
        unsigned short hi = f2b(v);
        a.d[y][n * 256 + k] = hi;
        a.d[y][n * 256 + 128 + k] = f2b(v - b2f(hi));
    } else {
        a.d[y][n * 128 + k] = f2b(v);
    }
}

// y0: Wu2t[e][f](+lo) = sum_d kw[f][d]*qw[e][d]; y1: Wvf2t[c][e](+lo) = sum_d vw[e][d]*fcw[d][c]
__global__ void build_small_kernel(const float* __restrict__ qw, const float* __restrict__ kw,
                                   const float* __restrict__ vw, const float* __restrict__ fcw,
                                   unsigned short* __restrict__ wu2t, unsigned short* __restrict__ wvf2t) {
    int y = blockIdx.y, i = blockIdx.x, j = threadIdx.x;
    float s = 0.f;
    if (y == 0) {
        for (int d = 0; d < 128; d++) s += kw[j * 128 + d] * qw[i * 128 + d];
        unsigned short hi = f2b(s);
        wu2t[i * 256 + j] = hi;
        wu2t[i * 256 + 128 + j] = f2b(s - b2f(hi));
    } else {
        for (int d = 0; d < 128; d++) s += vw[j * 128 + d] * fcw[d * 128 + i];
        unsigned short hi = f2b(s);
        wvf2t[i * 256 + j] = hi;
        wvf2t[i * 256 + 128 + j] = f2b(s - b2f(hi));
    }
}

// ---------------------------------------------------------------- MFMA GEMM  C[M,128] = epi(A[M,KD] @ W)
// Wt layout: [128 cols][KD] bf16.  LDS XOR swizzle: byte ^= (row&7)<<4.
struct MArgs {
    const unsigned short* A;
    const unsigned short* W0; const unsigned short* W1;
    const unsigned short* W2; const unsigned short* W3;
    const float* b0;
    void* C0; void* C1; void* C2; void* C3;
    unsigned short* Csplit;   // EPI 2
    const float* pe;          // EPI 2
    long row0;                // mode1 addressing + pe index
    int  M;
    int  mode;                // 0: A row = local row; 1: g=row0+i -> n=g/6,t=g%6, A row = t*N_+n
};

// EPI: 0 = bf16 out; 1 = +bias, bf16 out; 2 = +bias+pe, fp32 out + split out; 4 = fp32 out
template <int KD, int EPI>
__global__ __launch_bounds__(256) void mgemm_kernel(MArgs g) {
    constexpr int RB = KD * 2;
    __shared__ __align__(16) char As[128 * RB];
    __shared__ __align__(16) char Bs[128 * RB];
    int tid = threadIdx.x;
    int y = blockIdx.y;
    const unsigned short* W = (y == 0) ? g.W0 : (y == 1) ? g.W1 : (y == 2) ? g.W2 : g.W3;
    void* C = (y == 0) ? g.C0 : (y == 1) ? g.C1 : (y == 2) ? g.C2 : g.C3;
    int brow0 = blockIdx.x * 128;

    constexpr int CPR = KD / 8;          // 16B chunks per row
    constexpr int NIT = 128 * CPR / 256;
#pragma unroll
    for (int i = 0; i < NIT; i++) {
        int c = tid + i * 256;
        int row = c / CPR;
        int cb = (c % CPR) << 4;
        int scb = cb ^ ((row & 7) << 4);
        *(float4*)(Bs + row * RB + scb) = *(const float4*)((const char*)W + (size_t)row * RB + cb);
        int grow = brow0 + row;
        float4 av = make_float4(0.f, 0.f, 0.f, 0.f);
        if (grow < g.M) {
            long ar;
            if (g.mode == 0) ar = grow;
            else { long gg = g.row0 + grow; long n = gg / 6, t = gg - n * 6; ar = t * (long)N_ + n; }
            av = *(const float4*)((const char*)g.A + ar * (long)RB + cb);
        }
        *(float4*)(As + row * RB + scb) = av;
    }
    __syncthreads();

    int w = tid >> 6, l = tid & 63;
    int l15 = l & 15, lg = l >> 4;
    f32x4 acc[2][8];
#pragma unroll
    for (int a = 0; a < 2; a++)
#pragma unroll
        for (int b = 0; b < 8; b++) acc[a][b] = (f32x4)(0.f);

#pragma unroll
    for (int ks = 0; ks < KD / 32; ks++) {
        bf16x8 bf[8];
#pragma unroll
        for (int nt = 0; nt < 8; nt++) {
            int rn = nt * 16 + l15;
            int cbyte = (ks * 64 + lg * 16) ^ ((rn & 7) << 4);
            bf[nt] = *(const bf16x8*)(Bs + rn * RB + cbyte);
        }
#pragma unroll
        for (int mt = 0; mt < 2; mt++) {
            int rm = w * 32 + mt * 16 + l15;
            int cbyte = (ks * 64 + lg * 16) ^ ((rm & 7) << 4);
            bf16x8 af = *(const bf16x8*)(As + rm * RB + cbyte);
#pragma unroll
            for (int nt = 0; nt < 8; nt++)
                acc[mt][nt] = __builtin_amdgcn_mfma_f32_16x16x32_bf16(af, bf[nt], acc[mt][nt], 0, 0, 0);
        }
    }

#pragma unroll
    for (int mt = 0; mt < 2; mt++) {
#pragma unroll
        for (int r = 0; r < 4; r++) {
            int row = w * 32 + mt * 16 + lg * 4 + r;
            int grow = brow0 + row;
            if (grow >= g.M) continue;
            long t6 = 0;
            if (EPI == 2) t6 = (g.row0 + grow) % 6;
#pragma unroll
            for (int nt = 0; nt < 8; nt++) {
                int col = nt * 16 + l15;
                float v = acc[mt][nt][r];
                if (EPI == 1 || EPI == 2) v += g.b0[col];
                if (EPI == 2) v += g.pe[t6 * 128 + col];
                if (EPI == 0 || EPI == 1) {
                    ((unsigned short*)C)[(size_t)grow * 128 + col] = f2b(v);
                } else if (EPI == 4) {
                    ((float*)C)[(size_t)grow * 128 + col] = v;
                } else if (EPI == 2) {
                    ((float*)C)[(size_t)grow * 128 + col] = v;
                    unsigned short hi = f2b(v);
                    g.Csplit[(size_t)grow * 256 + col] = hi;
                    g.Csplit[(size_t)grow * 256 + 128 + col] = f2b(v - b2f(hi));
                }
            }
        }
    }
}

// ---------------------------------------------------------------- semantic w partials (MFMA + tanh reduce)
__global__ __launch_bounds__(256) void semw_kernel(const unsigned short* __restrict__ A,
                                                   const unsigned short* __restrict__ Wt,
                                                   const float* __restrict__ b1,
                                                   const float* __restrict__ w2,
                                                   float* __restrict__ partials, int M) {
    __shared__ __align__(16) char As[128 * 256];
    __shared__ __align__(16) char Bs[128 * 256];
    __shared__ float bs[2];
    int tid = threadIdx.x;
    if (tid < 2) bs[tid] = 0.f;
    int brow0 = blockIdx.x * 128;
#pragma unroll
    for (int i = 0; i < 8; i++) {
        int c = tid + i * 256;
        int row = c >> 4;
        int cb = (c & 15) << 4;
        int scb = cb ^ ((row & 7) << 4);
        *(float4*)(Bs + row * 256 + scb) = *(const float4*)((const char*)Wt + (size_t)row * 256 + cb);
        int grow = brow0 + row;
        float4 av = make_float4(0.f, 0.f, 0.f, 0.f);
        if (grow < M) av = *(const float4*)((const char*)A + (size_t)grow * 256 + cb);
        *(float4*)(As + row * 256 + scb) = av;
    }
    __syncthreads();
    int w = tid >> 6, l = tid & 63;
    int l15 = l & 15, lg = l >> 4;
    f32x4 acc[2][8];
#pragma unroll
    for (int a = 0; a < 2; a++)
#pragma unroll
        for (int b = 0; b < 8; b++) acc[a][b] = (f32x4)(0.f);
#pragma unroll
    for (int ks = 0; ks < 4; ks++) {
        bf16x8 bf[8];
#pragma unroll
        for (int nt = 0; nt < 8; nt++) {
            int rn = nt * 16 + l15;
            int cbyte = (ks * 64 + lg * 16) ^ ((rn & 7) << 4);
            bf[nt] = *(const bf16x8*)(Bs + rn * 256 + cbyte);
        }
#pragma unroll
        for (int mt = 0; mt < 2; mt++) {
            int rm = w * 32 + mt * 16 + l15;
            int cbyte = (ks * 64 + lg * 16) ^ ((rm & 7) << 4);
            bf16x8 af = *(const bf16x8*)(As + rm * 256 + cbyte);
#pragma unroll
            for (int nt = 0; nt < 8; nt++)
                acc[mt][nt] = __builtin_amdgcn_mfma_f32_16x16x32_bf16(af, bf[nt], acc[mt][nt], 0, 0, 0);
        }
    }
#pragma unroll
    for (int mt = 0; mt < 2; mt++) {
#pragma unroll
        for (int r = 0; r < 4; r++) {
            int row = w * 32 + mt * 16 + lg * 4 + r;
            int grow = brow0 + row;
            float s = 0.f;
#pragma unroll
            for (int nt = 0; nt < 8; nt++) {
                int col = nt * 16 + l15;
                s += tanhf(acc[mt][nt][r] + b1[col]) * w2[col];
            }
#pragma unroll
            for (int mask = 1; mask <= 8; mask <<= 1) s += __shfl_xor(s, mask);
            if (l15 == 0 && grow < M) atomicAdd(&bs[grow & 1], s);
        }
    }
    __syncthreads();
    if (tid < 2) partials[blockIdx.x * 2 + tid] = bs[tid];
}

__global__ __launch_bounds__(512) void beta_kernel(const float* __restrict__ partials, int nb,
                                                   float* __restrict__ beta) {
    float s0 = 0.f, s1 = 0.f;
    for (int i = threadIdx.x; i < nb; i += 512) { s0 += partials[i * 2]; s1 += partials[i * 2 + 1]; }
#pragma unroll
    for (int mask = 1; mask <= 32; mask <<= 1) { s0 += __shfl_xor(s0, mask); s1 += __shfl_xor(s1, mask); }
    __shared__ float w0[8], w1[8];
    int w = threadIdx.x >> 6;
    if ((threadIdx.x & 63) == 0) { w0[w] = s0; w1[w] = s1; }
    __syncthreads();
    if (threadIdx.x == 0) {
        float t0 = 0.f, t1 = 0.f;
        for (int i = 0; i < 8; i++) { t0 += w0[i]; t1 += w1[i]; }
        float m0 = t0 / (float)N_, m1 = t1 / (float)N_;
        float mx = fmaxf(m0, m1);
        float e0 = __expf(m0 - mx), e1 = __expf(m1 - mx);
        float inv = 1.f / (e0 + e1);
        beta[0] = e0 * inv; beta[1] = e1 * inv;
    }
}

// ---------------------------------------------------------------- GAT edge aggregation (bf16), one wave per dst node
__global__ __launch_bounds__(256) void gat_edge_kernel(const unsigned short* __restrict__ fsb,
                                                       const unsigned short* __restrict__ fdb,
                                                       const int* __restrict__ offsets,
                                                       const int* __restrict__ srcs_sorted,
                                                       const float* __restrict__ gat_attn,
                                                       const float* __restrict__ gat_bias,
                                                       unsigned short* __restrict__ hout) {
    int r = blockIdx.y;
    const unsigned short* fs = fsb + (size_t)r * N_ * 128;
    const unsigned short* fd = fdb + (size_t)r * N_ * 128;
    const int* offs = offsets + r * (N_ + 1);
    const int* srcs = srcs_sorted + (size_t)r * E_;
    int lane = threadIdx.x & 63;
    int wid = (blockIdx.x * blockDim.x + threadIdx.x) >> 6;
    int nw = (gridDim.x * blockDim.x) >> 6;
    float a0 = gat_attn[r * 128 + 2 * lane], a1 = gat_attn[r * 128 + 2 * lane + 1];
    float b0 = gat_bias[r * 128 + 2 * lane], b1 = gat_bias[r * 128 + 2 * lane + 1];
    for (int n = wid; n < N_; n += nw) {
        unsigned int fdp = *(const unsigned int*)(fd + (size_t)n * 128 + 2 * lane);
        float fd0 = b2f((unsigned short)fdp), fd1 = b2f((unsigned short)(fdp >> 16));
        int e0 = offs[n], e1 = offs[n + 1];
        float m = -1e30f, ssum = 0.f, acc0 = 0.f, acc1 = 0.f;
        float f0 = 0.f, f1 = 0.f;
        if (e0 < e1) {
            unsigned int fp = *(const unsigned int*)(fs + (size_t)srcs[e0] * 128 + 2 * lane);
            f0 = b2f((unsigned short)fp); f1 = b2f((unsigned short)(fp >> 16));
        }
        for (int e = e0; e < e1; e++) {
            float nf0 = 0.f, nf1 = 0.f;
            if (e + 1 < e1) {
                unsigned int fp = *(const unsigned int*)(fs + (size_t)srcs[e + 1] * 128 + 2 * lane);
                nf0 = b2f((unsigned short)fp); nf1 = b2f((unsigned short)(fp >> 16));
            }
            float t0 = f0 + fd0; t0 = (t0 > 0.f) ? t0 : 0.2f * t0;
            float t1 = f1 + fd1; t1 = (t1 > 0.f) ? t1 : 0.2f * t1;
            float v = a0 * t0 + a1 * t1;
#pragma unroll
            for (int mask = 1; mask <= 8; mask <<= 1) v += __shfl_xor(v, mask);
            float nm = fmaxf(m, v);
            float sc = __expf(m - nm);
            float p = __expf(v - nm);
            ssum = ssum * sc + p;
            acc0 = acc0 * sc + p * f0;
            acc1 = acc1 * sc + p * f1;
            m = nm;
            f0 = nf0; f1 = nf1;
        }
        float o0, o1;
        if (e1 > e0) { float inv = 1.f / ssum; o0 = acc0 * inv + b0; o1 = acc1 * inv + b1; }
        else { o0 = b0; o1 = b1; }
        unsigned int pk = (unsigned int)f2b(o0) | ((unsigned int)f2b(o1) << 16);
        *(unsigned int*)(hout + ((size_t)n * 2 + r) * 128 + 2 * lane) = pk;
    }
}

// ---------------------------------------------------------------- hsem: beta-mix + relu + bias + relu -> inter2 (hi/lo split)
__global__ void hsem_kernel(const unsigned short* __restrict__ h, const float* __restrict__ beta,
                            const float* __restrict__ h_bias, unsigned short* __restrict__ inter2, int t) {
    int idx = blockIdx.x * blockDim.x + threadIdx.x;
    if (idx >= N_ * 16) return;
    int n = idx >> 4, c8 = (idx & 15) * 8;
    float b0 = beta[0], b1 = beta[1];
    uint4 x0 = *(const uint4*)(h + (size_t)n * 256 + c8);
    uint4 x1 = *(const uint4*)(h + (size_t)n * 256 + 128 + c8);
    float4 hb0 = *(const float4*)(h_bias + c8);
    float4 hb1 = *(const float4*)(h_bias + c8 + 4);
    const unsigned int* p0 = (const unsigned int*)&x0;
    const unsigned int* p1 = (const unsigned int*)&x1;
    float hbv[8] = {hb0.x, hb0.y, hb0.z, hb0.w, hb1.x, hb1.y, hb1.z, hb1.w};
    union { unsigned short s[8]; uint4 u; } hi, lo;
#pragma unroll
    for (int i = 0; i < 8; i++) {
        unsigned short s0 = (i & 1) ? (unsigned short)(p0[i >> 1] >> 16) : (unsigned short)p0[i >> 1];
        unsigned short s1 = (i & 1) ? (unsigned short)(p1[i >> 1] >> 16) : (unsigned short)p1[i >> 1];
        float z = fmaxf(fmaxf(b0 * b2f(s0) + b1 * b2f(s1), 0.f) + hbv[i], 0.f);
        hi.s[i] = f2b(z);
        lo.s[i] = f2b(z - b2f(hi.s[i]));
    }
    *(uint4*)(inter2 + ((size_t)n * 6 + t) * 256 + c8) = hi.u;
    *(uint4*)(inter2 + ((size_t)n * 6 + t) * 256 + 128 + c8) = lo.u;
}

// ---------------------------------------------------------------- temporal attention + gated residual + LN
__global__ __launch_bounds__(256) void temporal_kernel(const float* __restrict__ hh,
                                                       const float* __restrict__ uu,
                                                       const unsigned short* __restrict__ wvv,
                                                       const unsigned short* __restrict__ rv,
                                                       const float* __restrict__ fc_b,
                                                       const float* __restrict__ res_alpha,
                                                       const float* __restrict__ ln_g,
                                                       const float* __restrict__ ln_b,
                                                       float* __restrict__ out, long n0) {
    int lane = threadIdx.x & 63;
    int wid = (blockIdx.x * blockDim.x + threadIdx.x) >> 6;
    if (wid >= CH_) return;
    long n = n0 + wid;
    size_t base = (size_t)wid * 6 * 128;
    float2 h2[6], u2[6];
    float wv2[6][2], rv2[6][2];
#pragma unroll
    for (int t = 0; t < 6; t++) {
        h2[t] = ((const float2*)(hh + base + t * 128))[lane];
        u2[t] = ((const float2*)(uu + base + t * 128))[lane];
        unsigned int wp = *(const unsigned int*)(wvv + base + t * 128 + 2 * lane);
        wv2[t][0] = b2f((unsigned short)wp); wv2[t][1] = b2f((unsigned short)(wp >> 16));
        unsigned int rp = *(const unsigned int*)(rv + base + t * 128 + 2 * lane);
        rv2[t][0] = b2f((unsigned short)rp); rv2[t][1] = b2f((unsigned short)(rp >> 16));
    }
    float sc[6][6];
#pragma unroll
    for (int t = 0; t < 6; t++)
#pragma unroll
        for (int s = 0; s < 6; s++)
            sc[t][s] = h2[t].x * u2[s].x + h2[t].y * u2[s].y;
#pragma unroll
    for (int mask = 1; mask <= 32; mask <<= 1)
#pragma unroll
        for (int t = 0; t < 6; t++)
#pragma unroll
            for (int s = 0; s < 6; s++)
                sc[t][s] += __shfl_xor(sc[t][s], mask);

    float a = 1.f / (1.f + __expf(-res_alpha[0]));
    float2 fb = ((const float2*)fc_b)[lane];
    float2 lg = ((const float2*)ln_g)[lane];
    float2 lb = ((const float2*)ln_b)[lane];
#pragma unroll
    for (int t = 0; t < 6; t++) {
        float mx = sc[t][0];
#pragma unroll
        for (int s = 1; s < 6; s++) mx = fmaxf(mx, sc[t][s]);
        float p[6]; float den = 0.f;
#pragma unroll
        for (int s = 0; s < 6; s++) { p[s] = __expf(sc[t][s] - mx); den += p[s]; }
        float inv = 1.f / den;
        float ox = 0.f, oy = 0.f;
#pragma unroll
        for (int s = 0; s < 6; s++) { ox += p[s] * wv2[s][0]; oy += p[s] * wv2[s][1]; }
        ox = fmaxf(ox * inv + fb.x, 0.f);
        oy = fmaxf(oy * inv + fb.y, 0.f);
        ox = ox * a + rv2[t][0] * (1.f - a);
        oy = oy * a + rv2[t][1] * (1.f - a);
        float s1 = ox + oy, s2 = ox * ox + oy * oy;
#pragma unroll
        for (int mask = 1; mask <= 32; mask <<= 1) {
            s1 += __shfl_xor(s1, mask);
            s2 += __shfl_xor(s2, mask);
        }
        float mu = s1 * (1.f / 128.f);
        float var = s2 * (1.f / 128.f) - mu * mu;
        float rs = rsqrtf(var + 1e-5f);
        float2 o;
        o.x = (ox - mu) * rs * lg.x + lb.x;
        o.y = (oy - mu) * rs * lg.y + lb.y;
        ((float2*)(out + ((size_t)t * N_ + n) * 128))[lane] = o;
    }
}

// ---------------------------------------------------------------- launch
extern "C" void kernel_launch(void* const* d_in, const int* in_sizes, int n_in,
                              void* d_out, int out_size, void* d_ws, size_t ws_size,
                              hipStream_t stream) {
    const float* x        = (const float*)d_in[0];
    const int*   src      = (const int*)d_in[1];
    const int*   dst      = (const int*)d_in[2];
    const float* gat_wsrc = (const float*)d_in[3];
    const float* gat_wdst = (const float*)d_in[4];
    const float* gat_attn = (const float*)d_in[5];
    const float* gat_bias = (const float*)d_in[6];
    const float* h_bias   = (const float*)d_in[7];
    const float* sem_w1   = (const float*)d_in[8];
    const float* sem_b1   = (const float*)d_in[9];
    const float* sem_w2   = (const float*)d_in[10];
    const float* proj_w   = (const float*)d_in[11];
    const float* proj_b   = (const float*)d_in[12];
    const float* qw       = (const float*)d_in[13];
    const float* kw       = (const float*)d_in[14];
    const float* vw       = (const float*)d_in[15];
    const float* fc_w     = (const float*)d_in[16];
    const float* fc_b     = (const float*)d_in[17];
    const float* res_w    = (const float*)d_in[18];
    const float* res_b    = (const float*)d_in[19];
    const float* res_alpha= (const float*)d_in[20];
    const float* ln_g     = (const float*)d_in[21];
    const float* ln_b     = (const float*)d_in[22];
    (void)in_sizes; (void)n_in; (void)out_size; (void)ws_size;

    char* ws = (char*)d_ws;
    size_t off = 0;
    auto alloc = [&](size_t bytes) -> void* {
        void* p = ws + off;
        off += (bytes + 255) & ~(size_t)255;
        return p;
    };
    int*   counts      = (int*)alloc((size_t)R_ * N_ * 4);
    int*   offsets     = (int*)alloc((size_t)R_ * (N_ + 1) * 4);
    int*   cursor      = (int*)alloc((size_t)R_ * N_ * 4);
    int*   srcs_sorted = (int*)alloc((size_t)R_ * E_ * 4);
    float* pe          = (float*)alloc(T_ * NH_ * 4);
    float* partials    = (float*)alloc((size_t)SEMW_BLOCKS * 2 * 4);
    float* beta        = (float*)alloc(256);
    unsigned short* wt_gs0   = (unsigned short*)alloc(16384 * 2);
    unsigned short* wt_gs1   = (unsigned short*)alloc(16384 * 2);
    unsigned short* wt_gd0   = (unsigned short*)alloc(16384 * 2);
    unsigned short* wt_gd1   = (unsigned short*)alloc(16384 * 2);
    unsigned short* wt_sem   = (unsigned short*)alloc(16384 * 2);
    unsigned short* wt_proj2 = (unsigned short*)alloc(32768 * 2);
    unsigned short* wt_res   = (unsigned short*)alloc(16384 * 2);
    unsigned short* wu2t     = (unsigned short*)alloc(32768 * 2);
    unsigned short* wvf2t    = (unsigned short*)alloc(32768 * 2);
    unsigned short* xb       = (unsigned short*)alloc((size_t)T_ * N_ * 128 * 2);   // 76.8 MB
    unsigned short* inter2   = (unsigned short*)alloc((size_t)N_ * T_ * 256 * 2);   // 153.6 MB
    char* region             = (char*)alloc((size_t)3 * N_ * 256 * 2);              // 76.8 MB

    // GAT-phase overlay
    unsigned short* fsb_b = (unsigned short*)region;                      // [R][N][128]
    unsigned short* fdb_b = fsb_b + (size_t)2 * N_ * 128;                 // [R][N][128]
    unsigned short* hbuf  = fdb_b + (size_t)2 * N_ * 128;                 // [N][R][128]
    // temporal-phase overlay (chunk: CH_ nodes = 37500 rows)
    float*          hh_f  = (float*)region;                               // 19.2 MB
    unsigned short* hh2   = (unsigned short*)(region + (size_t)19200 * 1024);
    float*          u_f   = (float*)(region + (size_t)38400 * 1024);
    unsigned short* wv_b  = (unsigned short*)(region + (size_t)57600 * 1024);
    unsigned short* rv_b  = (unsigned short*)(region + (size_t)67200 * 1024);

    // --- CSR + precomputes
    hipMemsetAsync(counts, 0, (size_t)R_ * N_ * 4, stream);
    hist_kernel<<<(R_ * E_ + 255) / 256, 256, 0, stream>>>(dst, counts);
    scan_kernel<<<R_, 1024, 0, stream>>>(counts, offsets, cursor);
    scatter_kernel<<<(R_ * E_ + 255) / 256, 256, 0, stream>>>(src, dst, cursor, srcs_sorted);
    pe_kernel<<<1, 128, 0, stream>>>(pe);
    cvt_x_kernel<<<18750, 256, 0, stream>>>(x, xb, (long)T_ * N_ * 128);
    CvtArgs ca;
    ca.s[0] = gat_wsrc;         ca.d[0] = wt_gs0;
    ca.s[1] = gat_wsrc + 16384; ca.d[1] = wt_gs1;
    ca.s[2] = gat_wdst;         ca.d[2] = wt_gd0;
    ca.s[3] = gat_wdst + 16384; ca.d[3] = wt_gd1;
    ca.s[4] = sem_w1;           ca.d[4] = wt_sem;
    ca.s[5] = proj_w;           ca.d[5] = wt_proj2;
    ca.s[6] = res_w;            ca.d[6] = wt_res;
    cvt_wt_kernel<<<dim3(128, 7), 128, 0, stream>>>(ca);
    build_small_kernel<<<dim3(128, 2), 128, 0, stream>>>(qw, kw, vw, fc_w, wu2t, wvf2t);

    // --- per-timestep GAT + semantic attention
    for (int t = 0; t < T_; t++) {
        MArgs ga{};
        ga.A = xb + (size_t)t * N_ * 128;
        ga.mode = 0; ga.row0 = 0; ga.M = N_;
        ga.W0 = wt_gs0; ga.C0 = fsb_b;
        ga.W1 = wt_gd0; ga.C1 = fdb_b;
        ga.W2 = wt_gs1; ga.C2 = fsb_b + (size_t)N_ * 128;
        ga.W3 = wt_gd1; ga.C3 = fdb_b + (size_t)N_ * 128;
        mgemm_kernel<128, 0><<<dim3((N_ + 127) / 128, 4), 256, 0, stream>>>(ga);

        gat_edge_kernel<<<dim3(2048, 2), 256, 0, stream>>>(fsb_b, fdb_b, offsets, srcs_sorted,
                                                           gat_attn, gat_bias, hbuf);

        semw_kernel<<<SEMW_BLOCKS, 256, 0, stream>>>(hbuf, wt_sem, sem_b1, sem_w2, partials, 2 * N_);
        beta_kernel<<<1, 512, 0, stream>>>(partials, SEMW_BLOCKS, beta);
        hsem_kernel<<<(N_ * 16 + 255) / 256, 256, 0, stream>>>(hbuf, beta, h_bias, inter2, t);
    }

    // --- temporal attention + residual + LN (chunked over nodes)
    for (int c = 0; c < N_ / CH_; c++) {
        long n0 = (long)c * CH_;
        long r0 = n0 * 6;
        int Mc = CH_ * 6;                  // 37500
        int nb = (Mc + 127) / 128;         // 293

        MArgs gp{};
        gp.A = inter2 + (size_t)r0 * 256; gp.mode = 0; gp.row0 = r0; gp.M = Mc;
        gp.W0 = wt_proj2; gp.b0 = proj_b; gp.C0 = hh_f; gp.Csplit = hh2; gp.pe = pe;
        mgemm_kernel<256, 2><<<dim3(nb, 1), 256, 0, stream>>>(gp);

        MArgs gu{};
        gu.A = hh2; gu.mode = 0; gu.row0 = 0; gu.M = Mc;
        gu.W0 = wu2t; gu.C0 = u_f;
        mgemm_kernel<256, 4><<<dim3(nb, 1), 256, 0, stream>>>(gu);

        MArgs gw{};
        gw.A = hh2; gw.mode = 0; gw.row0 = 0; gw.M = Mc;
        gw.W0 = wvf2t; gw.C0 = wv_b;
        mgemm_kernel<256, 0><<<dim3(nb, 1), 256, 0, stream>>>(gw);

        MArgs gr{};
        gr.A = xb; gr.mode = 1; gr.row0 = r0; gr.M = Mc;
        gr.W0 = wt_res; gr.b0 = res_b; gr.C0 = rv_b;
        mgemm_kernel<128, 1><<<dim3(nb, 1), 256, 0, stream>>>(gr);

        temporal_kernel<<<(CH_ + 3) / 4, 256, 0, stream>>>(hh_f, u_f, wv_b, rv_b, fc_b, res_alpha,
                                                           ln_g, ln_b, (float*)d_out, n0);
    }
}

// Round 4
// 1906.666 us; speedup vs baseline: 1.7352x; 1.5344x over previous
//
#include <hip/hip_runtime.h>
#include <math.h>

#define T_  6
#define N_  50000
#define NH_ 128
#define R_  2
#define E_  800000
#define CH_ 12500           // temporal chunk (nodes); 4 chunks
#define SEMW_BLOCKS ((2*N_ + 127)/128)   // 782

typedef __attribute__((ext_vector_type(8))) short bf16x8;
typedef __attribute__((ext_vector_type(4))) float f32x4;

__device__ inline unsigned short f2b(float f) {
    union { float f; unsigned int u; } v; v.f = f;
    unsigned int u = v.u;
    unsigned int r = (u + 0x7FFFu + ((u >> 16) & 1u)) >> 16;
    return (unsigned short)r;
}
__device__ inline float b2f(unsigned short h) {
    union { unsigned int u; float f; } v; v.u = ((unsigned int)h) << 16;
    return v.f;
}

// ---------------------------------------------------------------- CSR build
__global__ void hist_kernel(const int* __restrict__ dst, int* __restrict__ counts) {
    int j = blockIdx.x * blockDim.x + threadIdx.x;
    if (j < R_ * E_) atomicAdd(&counts[(j / E_) * N_ + dst[j]], 1);
}

__global__ __launch_bounds__(1024) void scan_kernel(const int* __restrict__ counts,
                                                    int* __restrict__ offsets,
                                                    int* __restrict__ cursor) {
    int r = blockIdx.x;
    __shared__ int sm[1024];
    __shared__ int carry;
    if (threadIdx.x == 0) carry = 0;
    __syncthreads();
    for (int base = 0; base < N_; base += 1024) {
        int i = base + threadIdx.x;
        int v = (i < N_) ? counts[r * N_ + i] : 0;
        sm[threadIdx.x] = v;
        __syncthreads();
        for (int off = 1; off < 1024; off <<= 1) {
            int t = 0;
            if (threadIdx.x >= off) t = sm[threadIdx.x - off];
            __syncthreads();
            sm[threadIdx.x] += t;
            __syncthreads();
        }
        int incl = sm[threadIdx.x];
        int run = carry;
        int excl = run + incl - v;
        if (i < N_) { offsets[r * (N_ + 1) + i] = excl; cursor[r * N_ + i] = excl; }
        __syncthreads();
        if (threadIdx.x == 1023) carry = run + incl;
        __syncthreads();
    }
    if (threadIdx.x == 0) offsets[r * (N_ + 1) + N_] = carry;
}

__global__ void scatter_kernel(const int* __restrict__ src, const int* __restrict__ dst,
                               int* __restrict__ cursor, int* __restrict__ srcs_sorted) {
    int j = blockIdx.x * blockDim.x + threadIdx.x;
    if (j < R_ * E_) {
        int r = j / E_;
        int pos = atomicAdd(&cursor[r * N_ + dst[j]], 1);
        srcs_sorted[(size_t)r * E_ + pos] = src[j];
    }
}

// ---------------------------------------------------------------- small precomputes
__global__ void pe_kernel(float* __restrict__ pe) {
    int c = threadIdx.x;
    int k = c & ~1;
    double div = exp((double)k * (-log(100000.0) / 128.0));
    for (int t = 0; t < T_; t++) {
        double pos = (double)(t + 1);
        double v = (c & 1) ? cos(pos * div) : sin(pos * div);
        pe[t * NH_ + c] = (float)v;
    }
}

__global__ void cvt_x_kernel(const float* __restrict__ in, unsigned short* __restrict__ out, long n) {
    long i = ((long)blockIdx.x * blockDim.x + threadIdx.x) * 8;
    if (i >= n) return;
    float4 a = *(const float4*)(in + i);
    float4 b = *(const float4*)(in + i + 4);
    union { unsigned short s[8]; uint4 u; } o;
    o.s[0] = f2b(a.x); o.s[1] = f2b(a.y); o.s[2] = f2b(a.z); o.s[3] = f2b(a.w);
    o.s[4] = f2b(b.x); o.s[5] = f2b(b.y); o.s[6] = f2b(b.z); o.s[7] = f2b(b.w);
    *(uint4*)(out + i) = o.u;
}

// transpose+convert 128x128 weights into Wt[n][k] bf16
struct CvtArgs {
    const float* s[6];
    unsigned short* d[6];
};
__global__ void cvt_wt_kernel(CvtArgs a) {
    int y = blockIdx.y, n = blockIdx.x, k = threadIdx.x;
    a.d[y][n * 128 + k] = f2b(a.s[y][k * 128 + n]);
}

// Mu[c][f] = sum_d kw[f][d]*qw[c][d];  Mwv[c][e] = sum_d vw[e][d]*fcw[d][c]
__global__ void build_m_kernel(const float* __restrict__ qw, const float* __restrict__ kw,
                               const float* __restrict__ vw, const float* __restrict__ fcw,
                               float* __restrict__ Mu, float* __restrict__ Mwv) {
    int y = blockIdx.y, c = blockIdx.x, f = threadIdx.x;
    float s = 0.f;
    if (y == 0) {
        for (int d = 0; d < 128; d++) s += kw[f * 128 + d] * qw[c * 128 + d];
        Mu[c * 128 + f] = s;
    } else {
        for (int d = 0; d < 128; d++) s += vw[f * 128 + d] * fcw[d * 128 + c];
        Mwv[c * 128 + f] = s;
    }
}

// folded temporal weights (Wt layout [c][k]):
// wt_hh[c][k]=proj[k][c]; wt_pu[c][k]=sum_f proj[k][f]*Mu[c][f]; wt_pwv[c][k]=sum_f proj[k][f]*Mwv[c][f]
__global__ void fold_w_kernel(const float* __restrict__ proj, const float* __restrict__ Mu,
                              const float* __restrict__ Mwv, unsigned short* __restrict__ wt_hh,
                              unsigned short* __restrict__ wt_pu, unsigned short* __restrict__ wt_pwv) {
    int y = blockIdx.y, c = blockIdx.x, k = threadIdx.x;
    if (y == 0) { wt_hh[c * 128 + k] = f2b(proj[k * 128 + c]); return; }
    const float* M = (y == 1) ? Mu : Mwv;
    float s = 0.f;
    for (int f = 0; f < 128; f++) s += proj[k * 128 + f] * M[c * 128 + f];
    ((y == 1) ? wt_pu : wt_pwv)[c * 128 + k] = f2b(s);
}

// cbuf[4][6][128]: y0 = proj_b+pe[t]; y1 = (proj_b+pe)@Mu^T; y2 = (proj_b+pe)@Mwv^T; y3 = res_b
__global__ void fold_c_kernel(const float* __restrict__ proj_b, const float* __restrict__ pe,
                              const float* __restrict__ Mu, const float* __restrict__ Mwv,
                              const float* __restrict__ res_b, float* __restrict__ cbuf) {
    int t = blockIdx.x, c = threadIdx.x;
    cbuf[0 * 768 + t * 128 + c] = proj_b[c] + pe[t * 128 + c];
    float s1 = 0.f, s2 = 0.f;
    for (int f = 0; f < 128; f++) {
        float b = proj_b[f] + pe[t * 128 + f];
        s1 += b * Mu[c * 128 + f];
        s2 += b * Mwv[c * 128 + f];
    }
    cbuf[1 * 768 + t * 128 + c] = s1;
    cbuf[2 * 768 + t * 128 + c] = s2;
    cbuf[3 * 768 + t * 128 + c] = res_b[c];
}

// ---------------------------------------------------------------- MFMA GEMM  C[M,128] = epi(A[M,128] @ Wt^T)
// Wt layout: [128 cols][128 k] bf16.  LDS XOR swizzle: byte ^= (row&7)<<4.
struct MArgs {
    const unsigned short* A;     // mode-0 base (pre-offset to chunk)
    const unsigned short* Axb;   // mode-1 base (y==3 when EPI==3)
    const unsigned short* W0; const unsigned short* W1;
    const unsigned short* W2; const unsigned short* W3;
    unsigned short* C0; unsigned short* C1; unsigned short* C2; unsigned short* C3;
    const float* cb;             // [4][6][128] (EPI 3)
    long row0;
    int  M;
};

// EPI: 0 = bf16 out; 3 = + cb[y][t6][col], bf16 out (y3 reads Axb via mode-1)
template <int EPI>
__global__ __launch_bounds__(256) void mgemm_kernel(MArgs g) {
    __shared__ __align__(16) char As[128 * 256];
    __shared__ __align__(16) char Bs[128 * 256];
    int tid = threadIdx.x;
    int y = blockIdx.y;
    const unsigned short* W = (y == 0) ? g.W0 : (y == 1) ? g.W1 : (y == 2) ? g.W2 : g.W3;
    unsigned short* C = (y == 0) ? g.C0 : (y == 1) ? g.C1 : (y == 2) ? g.C2 : g.C3;
    int brow0 = blockIdx.x * 128;
    bool m1 = (EPI == 3 && y == 3);
    const unsigned short* Abase = m1 ? g.Axb : g.A;

#pragma unroll
    for (int i = 0; i < 8; i++) {
        int c = tid + i * 256;
        int row = c >> 4;
        int cb = (c & 15) << 4;
        int scb = cb ^ ((row & 7) << 4);
        *(float4*)(Bs + row * 256 + scb) = *(const float4*)((const char*)W + (size_t)row * 256 + cb);
        int grow = brow0 + row;
        float4 av = make_float4(0.f, 0.f, 0.f, 0.f);
        if (grow < g.M) {
            long ar;
            if (!m1) ar = grow;
            else { long gg = g.row0 + grow; long n = gg / 6, t = gg - n * 6; ar = t * (long)N_ + n; }
            av = *(const float4*)((const char*)Abase + ar * 256 + cb);
        }
        *(float4*)(As + row * 256 + scb) = av;
    }
    __syncthreads();

    int w = tid >> 6, l = tid & 63;
    int l15 = l & 15, lg = l >> 4;
    f32x4 acc[2][8];
#pragma unroll
    for (int a = 0; a < 2; a++)
#pragma unroll
        for (int b = 0; b < 8; b++) acc[a][b] = (f32x4)(0.f);

#pragma unroll
    for (int ks = 0; ks < 4; ks++) {
        bf16x8 bf[8];
#pragma unroll
        for (int nt = 0; nt < 8; nt++) {
            int rn = nt * 16 + l15;
            int cbyte = (ks * 64 + lg * 16) ^ ((rn & 7) << 4);
            bf[nt] = *(const bf16x8*)(Bs + rn * 256 + cbyte);
        }
#pragma unroll
        for (int mt = 0; mt < 2; mt++) {
            int rm = w * 32 + mt * 16 + l15;
            int cbyte = (ks * 64 + lg * 16) ^ ((rm & 7) << 4);
            bf16x8 af = *(const bf16x8*)(As + rm * 256 + cbyte);
#pragma unroll
            for (int nt = 0; nt < 8; nt++)
                acc[mt][nt] = __builtin_amdgcn_mfma_f32_16x16x32_bf16(af, bf[nt], acc[mt][nt], 0, 0, 0);
        }
    }

#pragma unroll
    for (int mt = 0; mt < 2; mt++) {
#pragma unroll
        for (int r = 0; r < 4; r++) {
            int row = w * 32 + mt * 16 + lg * 4 + r;
            int grow = brow0 + row;
            if (grow >= g.M) continue;
            long t6 = 0;
            if (EPI == 3) t6 = (g.row0 + grow) % 6;
#pragma unroll
            for (int nt = 0; nt < 8; nt++) {
                int col = nt * 16 + l15;
                float v = acc[mt][nt][r];
                if (EPI == 3) v += g.cb[y * 768 + t6 * 128 + col];
                C[(size_t)grow * 128 + col] = f2b(v);
            }
        }
    }
}

// ---------------------------------------------------------------- semantic w partials (MFMA + tanh reduce)
__global__ __launch_bounds__(256) void semw_kernel(const unsigned short* __restrict__ A,
                                                   const unsigned short* __restrict__ Wt,
                                                   const float* __restrict__ b1,
                                                   const float* __restrict__ w2,
                                                   float* __restrict__ partials, int M) {
    __shared__ __align__(16) char As[128 * 256];
    __shared__ __align__(16) char Bs[128 * 256];
    __shared__ float bs[2];
    int tid = threadIdx.x;
    if (tid < 2) bs[tid] = 0.f;
    int brow0 = blockIdx.x * 128;
#pragma unroll
    for (int i = 0; i < 8; i++) {
        int c = tid + i * 256;
        int row = c >> 4;
        int cb = (c & 15) << 4;
        int scb = cb ^ ((row & 7) << 4);
        *(float4*)(Bs + row * 256 + scb) = *(const float4*)((const char*)Wt + (size_t)row * 256 + cb);
        int grow = brow0 + row;
        float4 av = make_float4(0.f, 0.f, 0.f, 0.f);
        if (grow < M) av = *(const float4*)((const char*)A + (size_t)grow * 256 + cb);
        *(float4*)(As + row * 256 + scb) = av;
    }
    __syncthreads();
    int w = tid >> 6, l = tid & 63;
    int l15 = l & 15, lg = l >> 4;
    f32x4 acc[2][8];
#pragma unroll
    for (int a = 0; a < 2; a++)
#pragma unroll
        for (int b = 0; b < 8; b++) acc[a][b] = (f32x4)(0.f);
#pragma unroll
    for (int ks = 0; ks < 4; ks++) {
        bf16x8 bf[8];
#pragma unroll
        for (int nt = 0; nt < 8; nt++) {
            int rn = nt * 16 + l15;
            int cbyte = (ks * 64 + lg * 16) ^ ((rn & 7) << 4);
            bf[nt] = *(const bf16x8*)(Bs + rn * 256 + cbyte);
        }
#pragma unroll
        for (int mt = 0; mt < 2; mt++) {
            int rm = w * 32 + mt * 16 + l15;
            int cbyte = (ks * 64 + lg * 16) ^ ((rm & 7) << 4);
            bf16x8 af = *(const bf16x8*)(As + rm * 256 + cbyte);
#pragma unroll
            for (int nt = 0; nt < 8; nt++)
                acc[mt][nt] = __builtin_amdgcn_mfma_f32_16x16x32_bf16(af, bf[nt], acc[mt][nt], 0, 0, 0);
        }
    }
#pragma unroll
    for (int mt = 0; mt < 2; mt++) {
#pragma unroll
        for (int r = 0; r < 4; r++) {
            int row = w * 32 + mt * 16 + lg * 4 + r;
            int grow = brow0 + row;
            float s = 0.f;
#pragma unroll
            for (int nt = 0; nt < 8; nt++) {
                int col = nt * 16 + l15;
                s += tanhf(acc[mt][nt][r] + b1[col]) * w2[col];
            }
#pragma unroll
            for (int mask = 1; mask <= 8; mask <<= 1) s += __shfl_xor(s, mask);
            if (l15 == 0 && grow < M) atomicAdd(&bs[grow & 1], s);
        }
    }
    __syncthreads();
    if (tid < 2) partials[blockIdx.x * 2 + tid] = bs[tid];
}

__global__ __launch_bounds__(512) void beta_kernel(const float* __restrict__ partials, int nb,
                                                   float* __restrict__ beta) {
    float s0 = 0.f, s1 = 0.f;
    for (int i = threadIdx.x; i < nb; i += 512) { s0 += partials[i * 2]; s1 += partials[i * 2 + 1]; }
#pragma unroll
    for (int mask = 1; mask <= 32; mask <<= 1) { s0 += __shfl_xor(s0, mask); s1 += __shfl_xor(s1, mask); }
    __shared__ float w0[8], w1[8];
    int w = threadIdx.x >> 6;
    if ((threadIdx.x & 63) == 0) { w0[w] = s0; w1[w] = s1; }
    __syncthreads();
    if (threadIdx.x == 0) {
        float t0 = 0.f, t1 = 0.f;
        for (int i = 0; i < 8; i++) { t0 += w0[i]; t1 += w1[i]; }
        float m0 = t0 / (float)N_, m1 = t1 / (float)N_;
        float mx = fmaxf(m0, m1);
        float e0 = __expf(m0 - mx), e1 = __expf(m1 - mx);
        float inv = 1.f / (e0 + e1);
        beta[0] = e0 * inv; beta[1] = e1 * inv;
    }
}

// ---------------------------------------------------------------- GAT edge aggregation (bf16, no-max softmax, 2-edge unroll)
__global__ __launch_bounds__(256) void gat_edge_kernel(const unsigned short* __restrict__ fsb,
                                                       const unsigned short* __restrict__ fdb,
                                                       const int* __restrict__ offsets,
                                                       const int* __restrict__ srcs_sorted,
                                                       const float* __restrict__ gat_attn,
                                                       const float* __restrict__ gat_bias,
                                                       unsigned short* __restrict__ hout) {
    int r = blockIdx.y;
    const unsigned short* fs = fsb + (size_t)r * N_ * 128;
    const unsigned short* fd = fdb + (size_t)r * N_ * 128;
    const int* offs = offsets + r * (N_ + 1);
    const int* srcs = srcs_sorted + (size_t)r * E_;
    int lane = threadIdx.x & 63;
    int wid = (blockIdx.x * blockDim.x + threadIdx.x) >> 6;
    int nw = (gridDim.x * blockDim.x) >> 6;
    float a0 = gat_attn[r * 128 + 2 * lane], a1 = gat_attn[r * 128 + 2 * lane + 1];
    float b0 = gat_bias[r * 128 + 2 * lane], b1 = gat_bias[r * 128 + 2 * lane + 1];
    for (int n = wid; n < N_; n += nw) {
        unsigned int fdp = *(const unsigned int*)(fd + (size_t)n * 128 + 2 * lane);
        float fd0 = b2f((unsigned short)fdp), fd1 = b2f((unsigned short)(fdp >> 16));
        int e0 = offs[n], e1 = offs[n + 1];
        float den = 0.f, acc0 = 0.f, acc1 = 0.f;
        unsigned int fpA = 0u, fpB = 0u;
        if (e0 < e1) fpA = *(const unsigned int*)(fs + (size_t)srcs[e0] * 128 + 2 * lane);
        if (e0 + 1 < e1) fpB = *(const unsigned int*)(fs + (size_t)srcs[e0 + 1] * 128 + 2 * lane);
        for (int e = e0; e < e1; e += 2) {
            unsigned int nA = 0u, nB = 0u;
            if (e + 2 < e1) nA = *(const unsigned int*)(fs + (size_t)srcs[e + 2] * 128 + 2 * lane);
            if (e + 3 < e1) nB = *(const unsigned int*)(fs + (size_t)srcs[e + 3] * 128 + 2 * lane);
            float fA0 = b2f((unsigned short)fpA), fA1 = b2f((unsigned short)(fpA >> 16));
            float fB0 = b2f((unsigned short)fpB), fB1 = b2f((unsigned short)(fpB >> 16));
            float tA0 = fA0 + fd0; tA0 = (tA0 > 0.f) ? tA0 : 0.2f * tA0;
            float tA1 = fA1 + fd1; tA1 = (tA1 > 0.f) ? tA1 : 0.2f * tA1;
            float tB0 = fB0 + fd0; tB0 = (tB0 > 0.f) ? tB0 : 0.2f * tB0;
            float tB1 = fB1 + fd1; tB1 = (tB1 > 0.f) ? tB1 : 0.2f * tB1;
            float vA = a0 * tA0 + a1 * tA1;
            float vB = a0 * tB0 + a1 * tB1;
#pragma unroll
            for (int mask = 1; mask <= 8; mask <<= 1) {
                vA += __shfl_xor(vA, mask);
                vB += __shfl_xor(vB, mask);
            }
            float pA = __expf(vA);                               // logits are O(1): no max needed in fp32
            float pB = (e + 1 < e1) ? __expf(vB) : 0.f;
            den += pA + pB;
            acc0 = fmaf(pA, fA0, fmaf(pB, fB0, acc0));
            acc1 = fmaf(pA, fA1, fmaf(pB, fB1, acc1));
            fpA = nA; fpB = nB;
        }
        float o0, o1;
        if (e1 > e0) { float inv = 1.f / den; o0 = fmaf(acc0, inv, b0); o1 = fmaf(acc1, inv, b1); }
        else { o0 = b0; o1 = b1; }
        unsigned int pk = (unsigned int)f2b(o0) | ((unsigned int)f2b(o1) << 16);
        *(unsigned int*)(hout + ((size_t)n * 2 + r) * 128 + 2 * lane) = pk;
    }
}

// ---------------------------------------------------------------- hsem: beta-mix + relu + bias + relu -> inter (bf16)
__global__ void hsem_kernel(const unsigned short* __restrict__ h, const float* __restrict__ beta,
                            const float* __restrict__ h_bias, unsigned short* __restrict__ inter, int t) {
    int idx = blockIdx.x * blockDim.x + threadIdx.x;
    if (idx >= N_ * 16) return;
    int n = idx >> 4, c8 = (idx & 15) * 8;
    float b0 = beta[0], b1 = beta[1];
    uint4 x0 = *(const uint4*)(h + (size_t)n * 256 + c8);
    uint4 x1 = *(const uint4*)(h + (size_t)n * 256 + 128 + c8);
    const unsigned int* p0 = (const unsigned int*)&x0;
    const unsigned int* p1 = (const unsigned int*)&x1;
    float4 hb0 = *(const float4*)(h_bias + c8);
    float4 hb1 = *(const float4*)(h_bias + c8 + 4);
    float hbv[8] = {hb0.x, hb0.y, hb0.z, hb0.w, hb1.x, hb1.y, hb1.z, hb1.w};
    union { unsigned short s[8]; uint4 u; } o;
#pragma unroll
    for (int i = 0; i < 8; i++) {
        unsigned short s0 = (i & 1) ? (unsigned short)(p0[i >> 1] >> 16) : (unsigned short)p0[i >> 1];
        unsigned short s1 = (i & 1) ? (unsigned short)(p1[i >> 1] >> 16) : (unsigned short)p1[i >> 1];
        float z = fmaxf(fmaxf(b0 * b2f(s0) + b1 * b2f(s1), 0.f) + hbv[i], 0.f);
        o.s[i] = f2b(z);
    }
    *(uint4*)(inter + ((size_t)n * 6 + t) * 128 + c8) = o.u;
}

// ---------------------------------------------------------------- temporal attention + gated residual + LN (all-bf16 in)
__global__ __launch_bounds__(256) void temporal_kernel(const unsigned short* __restrict__ hh,
                                                       const unsigned short* __restrict__ uu,
                                                       const unsigned short* __restrict__ wvv,
                                                       const unsigned short* __restrict__ rv,
                                                       const float* __restrict__ fc_b,
                                                       const float* __restrict__ res_alpha,
                                                       const float* __restrict__ ln_g,
                                                       const float* __restrict__ ln_b,
                                                       float* __restrict__ out, long n0) {
    int lane = threadIdx.x & 63;
    int wid = (blockIdx.x * blockDim.x + threadIdx.x) >> 6;
    if (wid >= CH_) return;
    long n = n0 + wid;
    size_t base = (size_t)wid * 6 * 128 + 2 * lane;
    float h2[6][2], u2[6][2], wv2[6][2], rv2[6][2];
#pragma unroll
    for (int t = 0; t < 6; t++) {
        unsigned int hp = *(const unsigned int*)(hh + base + t * 128);
        h2[t][0] = b2f((unsigned short)hp); h2[t][1] = b2f((unsigned short)(hp >> 16));
        unsigned int up = *(const unsigned int*)(uu + base + t * 128);
        u2[t][0] = b2f((unsigned short)up); u2[t][1] = b2f((unsigned short)(up >> 16));
        unsigned int wp = *(const unsigned int*)(wvv + base + t * 128);
        wv2[t][0] = b2f((unsigned short)wp); wv2[t][1] = b2f((unsigned short)(wp >> 16));
        unsigned int rp = *(const unsigned int*)(rv + base + t * 128);
        rv2[t][0] = b2f((unsigned short)rp); rv2[t][1] = b2f((unsigned short)(rp >> 16));
    }
    float sc[6][6];
#pragma unroll
    for (int t = 0; t < 6; t++)
#pragma unroll
        for (int s = 0; s < 6; s++)
            sc[t][s] = h2[t][0] * u2[s][0] + h2[t][1] * u2[s][1];
#pragma unroll
    for (int mask = 1; mask <= 32; mask <<= 1)
#pragma unroll
        for (int t = 0; t < 6; t++)
#pragma unroll
            for (int s = 0; s < 6; s++)
                sc[t][s] += __shfl_xor(sc[t][s], mask);

    float a = 1.f / (1.f + __expf(-res_alpha[0]));
    float2 fb = ((const float2*)fc_b)[lane];
    float2 lg = ((const float2*)ln_g)[lane];
    float2 lb = ((const float2*)ln_b)[lane];
#pragma unroll
    for (int t = 0; t < 6; t++) {
        float mx = sc[t][0];
#pragma unroll
        for (int s = 1; s < 6; s++) mx = fmaxf(mx, sc[t][s]);
        float p[6]; float den = 0.f;
#pragma unroll
        for (int s = 0; s < 6; s++) { p[s] = __expf(sc[t][s] - mx); den += p[s]; }
        float inv = 1.f / den;
        float ox = 0.f, oy = 0.f;
#pragma unroll
        for (int s = 0; s < 6; s++) { ox += p[s] * wv2[s][0]; oy += p[s] * wv2[s][1]; }
        ox = fmaxf(ox * inv + fb.x, 0.f);
        oy = fmaxf(oy * inv + fb.y, 0.f);
        ox = ox * a + rv2[t][0] * (1.f - a);
        oy = oy * a + rv2[t][1] * (1.f - a);
        float s1 = ox + oy, s2 = ox * ox + oy * oy;
#pragma unroll
        for (int mask = 1; mask <= 32; mask <<= 1) {
            s1 += __shfl_xor(s1, mask);
            s2 += __shfl_xor(s2, mask);
        }
        float mu = s1 * (1.f / 128.f);
        float var = s2 * (1.f / 128.f) - mu * mu;
        float rs = rsqrtf(var + 1e-5f);
        float2 o;
        o.x = (ox - mu) * rs * lg.x + lb.x;
        o.y = (oy - mu) * rs * lg.y + lb.y;
        ((float2*)(out + ((size_t)t * N_ + n) * 128))[lane] = o;
    }
}

// ---------------------------------------------------------------- launch
extern "C" void kernel_launch(void* const* d_in, const int* in_sizes, int n_in,
                              void* d_out, int out_size, void* d_ws, size_t ws_size,
                              hipStream_t stream) {
    const float* x        = (const float*)d_in[0];
    const int*   src      = (const int*)d_in[1];
    const int*   dst      = (const int*)d_in[2];
    const float* gat_wsrc = (const float*)d_in[3];
    const float* gat_wdst = (const float*)d_in[4];
    const float* gat_attn = (const float*)d_in[5];
    const float* gat_bias = (const float*)d_in[6];
    const float* h_bias   = (const float*)d_in[7];
    const float* sem_w1   = (const float*)d_in[8];
    const float* sem_b1   = (const float*)d_in[9];
    const float* sem_w2   = (const float*)d_in[10];
    const float* proj_w   = (const float*)d_in[11];
    const float* proj_b   = (const float*)d_in[12];
    const float* qw       = (const float*)d_in[13];
    const float* kw       = (const float*)d_in[14];
    const float* vw       = (const float*)d_in[15];
    const float* fc_w     = (const float*)d_in[16];
    const float* fc_b     = (const float*)d_in[17];
    const float* res_w    = (const float*)d_in[18];
    const float* res_b    = (const float*)d_in[19];
    const float* res_alpha= (const float*)d_in[20];
    const float* ln_g     = (const float*)d_in[21];
    const float* ln_b     = (const float*)d_in[22];
    (void)in_sizes; (void)n_in; (void)out_size; (void)ws_size;

    char* ws = (char*)d_ws;
    size_t off = 0;
    auto alloc = [&](size_t bytes) -> void* {
        void* p = ws + off;
        off += (bytes + 255) & ~(size_t)255;
        return p;
    };
    int*   counts      = (int*)alloc((size_t)R_ * N_ * 4);
    int*   offsets     = (int*)alloc((size_t)R_ * (N_ + 1) * 4);
    int*   cursor      = (int*)alloc((size_t)R_ * N_ * 4);
    int*   srcs_sorted = (int*)alloc((size_t)R_ * E_ * 4);
    float* pe          = (float*)alloc(T_ * NH_ * 4);
    float* partials    = (float*)alloc((size_t)SEMW_BLOCKS * 2 * 4);
    float* beta        = (float*)alloc(256);
    float* Mu          = (float*)alloc(16384 * 4);
    float* Mwv         = (float*)alloc(16384 * 4);
    float* cbuf        = (float*)alloc(4 * 768 * 4);
    unsigned short* wt_gs0  = (unsigned short*)alloc(16384 * 2);
    unsigned short* wt_gs1  = (unsigned short*)alloc(16384 * 2);
    unsigned short* wt_gd0  = (unsigned short*)alloc(16384 * 2);
    unsigned short* wt_gd1  = (unsigned short*)alloc(16384 * 2);
    unsigned short* wt_sem  = (unsigned short*)alloc(16384 * 2);
    unsigned short* wt_res  = (unsigned short*)alloc(16384 * 2);
    unsigned short* wt_hh   = (unsigned short*)alloc(16384 * 2);
    unsigned short* wt_pu   = (unsigned short*)alloc(16384 * 2);
    unsigned short* wt_pwv  = (unsigned short*)alloc(16384 * 2);
    unsigned short* xb      = (unsigned short*)alloc((size_t)T_ * N_ * 128 * 2);   // 76.8 MB
    unsigned short* inter   = (unsigned short*)alloc((size_t)N_ * T_ * 128 * 2);   // 76.8 MB
    char* region            = (char*)alloc((size_t)6 * N_ * 128 * 2);              // 76.8 MB

    // GAT-phase overlay
    unsigned short* fsb_b = (unsigned short*)region;                      // [R][N][128]
    unsigned short* fdb_b = fsb_b + (size_t)2 * N_ * 128;                 // [R][N][128]
    unsigned short* hbuf  = fdb_b + (size_t)2 * N_ * 128;                 // [N][R][128]
    // temporal-phase overlay (chunk: CH_ nodes = 75000 rows, 19.2 MB per buffer)
    unsigned short* hh_b = (unsigned short*)region;
    unsigned short* u_b  = hh_b + (size_t)CH_ * 6 * 128;
    unsigned short* wv_b = u_b + (size_t)CH_ * 6 * 128;
    unsigned short* rv_b = wv_b + (size_t)CH_ * 6 * 128;

    // --- CSR + precomputes
    hipMemsetAsync(counts, 0, (size_t)R_ * N_ * 4, stream);
    hist_kernel<<<(R_ * E_ + 255) / 256, 256, 0, stream>>>(dst, counts);
    scan_kernel<<<R_, 1024, 0, stream>>>(counts, offsets, cursor);
    scatter_kernel<<<(R_ * E_ + 255) / 256, 256, 0, stream>>>(src, dst, cursor, srcs_sorted);
    pe_kernel<<<1, 128, 0, stream>>>(pe);
    cvt_x_kernel<<<18750, 256, 0, stream>>>(x, xb, (long)T_ * N_ * 128);
    CvtArgs ca;
    ca.s[0] = gat_wsrc;         ca.d[0] = wt_gs0;
    ca.s[1] = gat_wsrc + 16384; ca.d[1] = wt_gs1;
    ca.s[2] = gat_wdst;         ca.d[2] = wt_gd0;
    ca.s[3] = gat_wdst + 16384; ca.d[3] = wt_gd1;
    ca.s[4] = sem_w1;           ca.d[4] = wt_sem;
    ca.s[5] = res_w;            ca.d[5] = wt_res;
    cvt_wt_kernel<<<dim3(128, 6), 128, 0, stream>>>(ca);
    build_m_kernel<<<dim3(128, 2), 128, 0, stream>>>(qw, kw, vw, fc_w, Mu, Mwv);
    fold_w_kernel<<<dim3(128, 3), 128, 0, stream>>>(proj_w, Mu, Mwv, wt_hh, wt_pu, wt_pwv);
    fold_c_kernel<<<6, 128, 0, stream>>>(proj_b, pe, Mu, Mwv, res_b, cbuf);

    // --- per-timestep GAT + semantic attention
    for (int t = 0; t < T_; t++) {
        MArgs ga{};
        ga.A = xb + (size_t)t * N_ * 128;
        ga.row0 = 0; ga.M = N_;
        ga.W0 = wt_gs0; ga.C0 = fsb_b;
        ga.W1 = wt_gd0; ga.C1 = fdb_b;
        ga.W2 = wt_gs1; ga.C2 = fsb_b + (size_t)N_ * 128;
        ga.W3 = wt_gd1; ga.C3 = fdb_b + (size_t)N_ * 128;
        mgemm_kernel<0><<<dim3((N_ + 127) / 128, 4), 256, 0, stream>>>(ga);

        gat_edge_kernel<<<dim3(2048, 2), 256, 0, stream>>>(fsb_b, fdb_b, offsets, srcs_sorted,
                                                           gat_attn, gat_bias, hbuf);

        semw_kernel<<<SEMW_BLOCKS, 256, 0, stream>>>(hbuf, wt_sem, sem_b1, sem_w2, partials, 2 * N_);
        beta_kernel<<<1, 512, 0, stream>>>(partials, SEMW_BLOCKS, beta);
        hsem_kernel<<<(N_ * 16 + 255) / 256, 256, 0, stream>>>(hbuf, beta, h_bias, inter, t);
    }

    // --- temporal attention + residual + LN (chunked over nodes; 4 independent folded GEMMs)
    for (int c = 0; c < N_ / CH_; c++) {
        long n0 = (long)c * CH_;
        long r0 = n0 * 6;
        int Mc = CH_ * 6;                  // 75000
        int nb = (Mc + 127) / 128;         // 586

        MArgs gt{};
        gt.A = inter + (size_t)r0 * 128;
        gt.Axb = xb;
        gt.row0 = r0; gt.M = Mc; gt.cb = cbuf;
        gt.W0 = wt_hh;  gt.C0 = hh_b;
        gt.W1 = wt_pu;  gt.C1 = u_b;
        gt.W2 = wt_pwv; gt.C2 = wv_b;
        gt.W3 = wt_res; gt.C3 = rv_b;
        mgemm_kernel<3><<<dim3(nb, 4), 256, 0, stream>>>(gt);

        temporal_kernel<<<(CH_ + 3) / 4, 256, 0, stream>>>(hh_b, u_b, wv_b, rv_b, fc_b, res_alpha,
                                                           ln_g, ln_b, (float*)d_out, n0);
    }
}

// Round 5
// 1770.235 us; speedup vs baseline: 1.8689x; 1.0771x over previous
//
#include <hip/hip_runtime.h>
#include <math.h>

#define T_  6
#define N_  50000
#define NH_ 128
#define R_  2
#define E_  800000
#define SEMW_BLOCKS ((2*N_ + 127)/128)   // 782

typedef __attribute__((ext_vector_type(8))) short bf16x8;
typedef __attribute__((ext_vector_type(4))) float f32x4;

__device__ inline unsigned short f2b(float f) {
    union { float f; unsigned int u; } v; v.f = f;
    unsigned int u = v.u;
    unsigned int r = (u + 0x7FFFu + ((u >> 16) & 1u)) >> 16;
    return (unsigned short)r;
}
__device__ inline float b2f(unsigned short h) {
    union { unsigned int u; float f; } v; v.u = ((unsigned int)h) << 16;
    return v.f;
}

// ---------------------------------------------------------------- CSR build
__global__ void hist_kernel(const int* __restrict__ dst, int* __restrict__ counts) {
    int j = blockIdx.x * blockDim.x + threadIdx.x;
    if (j < R_ * E_) atomicAdd(&counts[(j / E_) * N_ + dst[j]], 1);
}

__global__ __launch_bounds__(1024) void scan_kernel(const int* __restrict__ counts,
                                                    int* __restrict__ offsets,
                                                    int* __restrict__ cursor) {
    int r = blockIdx.x;
    __shared__ int sm[1024];
    __shared__ int carry;
    if (threadIdx.x == 0) carry = 0;
    __syncthreads();
    for (int base = 0; base < N_; base += 1024) {
        int i = base + threadIdx.x;
        int v = (i < N_) ? counts[r * N_ + i] : 0;
        sm[threadIdx.x] = v;
        __syncthreads();
        for (int off = 1; off < 1024; off <<= 1) {
            int t = 0;
            if (threadIdx.x >= off) t = sm[threadIdx.x - off];
            __syncthreads();
            sm[threadIdx.x] += t;
            __syncthreads();
        }
        int incl = sm[threadIdx.x];
        int run = carry;
        int excl = run + incl - v;
        if (i < N_) { offsets[r * (N_ + 1) + i] = excl; cursor[r * N_ + i] = excl; }
        __syncthreads();
        if (threadIdx.x == 1023) carry = run + incl;
        __syncthreads();
    }
    if (threadIdx.x == 0) offsets[r * (N_ + 1) + N_] = carry;
}

__global__ void scatter_kernel(const int* __restrict__ src, const int* __restrict__ dst,
                               int* __restrict__ cursor, int* __restrict__ srcs_sorted) {
    int j = blockIdx.x * blockDim.x + threadIdx.x;
    if (j < R_ * E_) {
        int r = j / E_;
        int pos = atomicAdd(&cursor[r * N_ + dst[j]], 1);
        srcs_sorted[(size_t)r * E_ + pos] = src[j];
    }
}

// ---------------------------------------------------------------- small precomputes
__global__ void pe_kernel(float* __restrict__ pe) {
    int c = threadIdx.x;
    int k = c & ~1;
    double div = exp((double)k * (-log(100000.0) / 128.0));
    for (int t = 0; t < T_; t++) {
        double pos = (double)(t + 1);
        double v = (c & 1) ? cos(pos * div) : sin(pos * div);
        pe[t * NH_ + c] = (float)v;
    }
}

__global__ void cvt_x_kernel(const float* __restrict__ in, unsigned short* __restrict__ out, long n) {
    long i = ((long)blockIdx.x * blockDim.x + threadIdx.x) * 8;
    if (i >= n) return;
    float4 a = *(const float4*)(in + i);
    float4 b = *(const float4*)(in + i + 4);
    union { unsigned short s[8]; uint4 u; } o;
    o.s[0] = f2b(a.x); o.s[1] = f2b(a.y); o.s[2] = f2b(a.z); o.s[3] = f2b(a.w);
    o.s[4] = f2b(b.x); o.s[5] = f2b(b.y); o.s[6] = f2b(b.z); o.s[7] = f2b(b.w);
    *(uint4*)(out + i) = o.u;
}

// transpose+convert 128x128 weights into Wt[n][k] bf16
struct CvtArgs {
    const float* s[6];
    unsigned short* d[6];
};
__global__ void cvt_wt_kernel(CvtArgs a) {
    int y = blockIdx.y, n = blockIdx.x, k = threadIdx.x;
    a.d[y][n * 128 + k] = f2b(a.s[y][k * 128 + n]);
}

// Mu[c][f] = sum_d kw[f][d]*qw[c][d];  Mwv[c][e] = sum_d vw[e][d]*fcw[d][c]
__global__ void build_m_kernel(const float* __restrict__ qw, const float* __restrict__ kw,
                               const float* __restrict__ vw, const float* __restrict__ fcw,
                               float* __restrict__ Mu, float* __restrict__ Mwv) {
    int y = blockIdx.y, c = blockIdx.x, f = threadIdx.x;
    float s = 0.f;
    if (y == 0) {
        for (int d = 0; d < 128; d++) s += kw[f * 128 + d] * qw[c * 128 + d];
        Mu[c * 128 + f] = s;
    } else {
        for (int d = 0; d < 128; d++) s += vw[f * 128 + d] * fcw[d * 128 + c];
        Mwv[c * 128 + f] = s;
    }
}

__global__ void fold_w_kernel(const float* __restrict__ proj, const float* __restrict__ Mu,
                              const float* __restrict__ Mwv, unsigned short* __restrict__ wt_hh,
                              unsigned short* __restrict__ wt_pu, unsigned short* __restrict__ wt_pwv) {
    int y = blockIdx.y, c = blockIdx.x, k = threadIdx.x;
    if (y == 0) { wt_hh[c * 128 + k] = f2b(proj[k * 128 + c]); return; }
    const float* M = (y == 1) ? Mu : Mwv;
    float s = 0.f;
    for (int f = 0; f < 128; f++) s += proj[k * 128 + f] * M[c * 128 + f];
    ((y == 1) ? wt_pu : wt_pwv)[c * 128 + k] = f2b(s);
}

// cbuf[4][6][128]: y0 = proj_b+pe[t]; y1 = (proj_b+pe)@Mu^T; y2 = (proj_b+pe)@Mwv^T; y3 = res_b
__global__ void fold_c_kernel(const float* __restrict__ proj_b, const float* __restrict__ pe,
                              const float* __restrict__ Mu, const float* __restrict__ Mwv,
                              const float* __restrict__ res_b, float* __restrict__ cbuf) {
    int t = blockIdx.x, c = threadIdx.x;
    cbuf[0 * 768 + t * 128 + c] = proj_b[c] + pe[t * 128 + c];
    float s1 = 0.f, s2 = 0.f;
    for (int f = 0; f < 128; f++) {
        float b = proj_b[f] + pe[t * 128 + f];
        s1 += b * Mu[c * 128 + f];
        s2 += b * Mwv[c * 128 + f];
    }
    cbuf[1 * 768 + t * 128 + c] = s1;
    cbuf[2 * 768 + t * 128 + c] = s2;
    cbuf[3 * 768 + t * 128 + c] = res_b[c];
}

// ---------------------------------------------------------------- MFMA GEMM  C[M,128] = epi(A[M,128] @ Wt^T)
struct MArgs {
    const unsigned short* A;     // mode-0 base
    const unsigned short* Axb;   // mode-1 base (y==3 when EPI==3)
    const unsigned short* W0; const unsigned short* W1;
    const unsigned short* W2; const unsigned short* W3;
    unsigned short* C0; unsigned short* C1; unsigned short* C2; unsigned short* C3;
    const float* cb;             // [4][6][128] (EPI 3)
    long row0;
    int  M;
};

// EPI: 0 = bf16 out; 3 = + cb[y][t6][col], bf16 out (y3 reads Axb via mode-1)
template <int EPI>
__global__ __launch_bounds__(256) void mgemm_kernel(MArgs g) {
    __shared__ __align__(16) char As[128 * 256];
    __shared__ __align__(16) char Bs[128 * 256];
    int tid = threadIdx.x;
    int y = blockIdx.y;
    const unsigned short* W = (y == 0) ? g.W0 : (y == 1) ? g.W1 : (y == 2) ? g.W2 : g.W3;
    unsigned short* C = (y == 0) ? g.C0 : (y == 1) ? g.C1 : (y == 2) ? g.C2 : g.C3;
    int brow0 = blockIdx.x * 128;
    bool m1 = (EPI == 3 && y == 3);
    const unsigned short* Abase = m1 ? g.Axb : g.A;

#pragma unroll
    for (int i = 0; i < 8; i++) {
        int c = tid + i * 256;
        int row = c >> 4;
        int cb = (c & 15) << 4;
        int scb = cb ^ ((row & 7) << 4);
        *(float4*)(Bs + row * 256 + scb) = *(const float4*)((const char*)W + (size_t)row * 256 + cb);
        int grow = brow0 + row;
        float4 av = make_float4(0.f, 0.f, 0.f, 0.f);
        if (grow < g.M) {
            long ar;
            if (!m1) ar = grow;
            else { long gg = g.row0 + grow; long n = gg / 6, t = gg - n * 6; ar = t * (long)N_ + n; }
            av = *(const float4*)((const char*)Abase + ar * 256 + cb);
        }
        *(float4*)(As + row * 256 + scb) = av;
    }
    __syncthreads();

    int w = tid >> 6, l = tid & 63;
    int l15 = l & 15, lg = l >> 4;
    f32x4 acc[2][8];
#pragma unroll
    for (int a = 0; a < 2; a++)
#pragma unroll
        for (int b = 0; b < 8; b++) acc[a][b] = (f32x4)(0.f);

#pragma unroll
    for (int ks = 0; ks < 4; ks++) {
        bf16x8 bf[8];
#pragma unroll
        for (int nt = 0; nt < 8; nt++) {
            int rn = nt * 16 + l15;
            int cbyte = (ks * 64 + lg * 16) ^ ((rn & 7) << 4);
            bf[nt] = *(const bf16x8*)(Bs + rn * 256 + cbyte);
        }
#pragma unroll
        for (int mt = 0; mt < 2; mt++) {
            int rm = w * 32 + mt * 16 + l15;
            int cbyte = (ks * 64 + lg * 16) ^ ((rm & 7) << 4);
            bf16x8 af = *(const bf16x8*)(As + rm * 256 + cbyte);
#pragma unroll
            for (int nt = 0; nt < 8; nt++)
                acc[mt][nt] = __builtin_amdgcn_mfma_f32_16x16x32_bf16(af, bf[nt], acc[mt][nt], 0, 0, 0);
        }
    }

#pragma unroll
    for (int mt = 0; mt < 2; mt++) {
#pragma unroll
        for (int r = 0; r < 4; r++) {
            int row = w * 32 + mt * 16 + lg * 4 + r;
            int grow = brow0 + row;
            if (grow >= g.M) continue;
            long t6 = 0;
            if (EPI == 3) t6 = (g.row0 + grow) % 6;
#pragma unroll
            for (int nt = 0; nt < 8; nt++) {
                int col = nt * 16 + l15;
                float v = acc[mt][nt][r];
                if (EPI == 3) v += g.cb[y * 768 + t6 * 128 + col];
                C[(size_t)grow * 128 + col] = f2b(v);
            }
        }
    }
}

// ---------------------------------------------------------------- semantic w partials (batched over t via blockIdx.y)
__global__ __launch_bounds__(256) void semw_kernel(const unsigned short* __restrict__ Abase,
                                                   const unsigned short* __restrict__ Wt,
                                                   const float* __restrict__ b1,
                                                   const float* __restrict__ w2,
                                                   float* __restrict__ partials) {
    __shared__ __align__(16) char As[128 * 256];
    __shared__ __align__(16) char Bs[128 * 256];
    __shared__ float bs[2];
    int tid = threadIdx.x;
    if (tid < 2) bs[tid] = 0.f;
    int tl = blockIdx.y;
    const unsigned short* A = Abase + (size_t)tl * N_ * 256;
    const int M = 2 * N_;
    int brow0 = blockIdx.x * 128;
#pragma unroll
    for (int i = 0; i < 8; i++) {
        int c = tid + i * 256;
        int row = c >> 4;
        int cb = (c & 15) << 4;
        int scb = cb ^ ((row & 7) << 4);
        *(float4*)(Bs + row * 256 + scb) = *(const float4*)((const char*)Wt + (size_t)row * 256 + cb);
        int grow = brow0 + row;
        float4 av = make_float4(0.f, 0.f, 0.f, 0.f);
        if (grow < M) av = *(const float4*)((const char*)A + (size_t)grow * 256 + cb);
        *(float4*)(As + row * 256 + scb) = av;
    }
    __syncthreads();
    int w = tid >> 6, l = tid & 63;
    int l15 = l & 15, lg = l >> 4;
    f32x4 acc[2][8];
#pragma unroll
    for (int a = 0; a < 2; a++)
#pragma unroll
        for (int b = 0; b < 8; b++) acc[a][b] = (f32x4)(0.f);
#pragma unroll
    for (int ks = 0; ks < 4; ks++) {
        bf16x8 bf[8];
#pragma unroll
        for (int nt = 0; nt < 8; nt++) {
            int rn = nt * 16 + l15;
            int cbyte = (ks * 64 + lg * 16) ^ ((rn & 7) << 4);
            bf[nt] = *(const bf16x8*)(Bs + rn * 256 + cbyte);
        }
#pragma unroll
        for (int mt = 0; mt < 2; mt++) {
            int rm = w * 32 + mt * 16 + l15;
            int cbyte = (ks * 64 + lg * 16) ^ ((rm & 7) << 4);
            bf16x8 af = *(const bf16x8*)(As + rm * 256 + cbyte);
#pragma unroll
            for (int nt = 0; nt < 8; nt++)
                acc[mt][nt] = __builtin_amdgcn_mfma_f32_16x16x32_bf16(af, bf[nt], acc[mt][nt], 0, 0, 0);
        }
    }
#pragma unroll
    for (int mt = 0; mt < 2; mt++) {
#pragma unroll
        for (int r = 0; r < 4; r++) {
            int row = w * 32 + mt * 16 + lg * 4 + r;
            int grow = brow0 + row;
            float s = 0.f;
#pragma unroll
            for (int nt = 0; nt < 8; nt++) {
                int col = nt * 16 + l15;
                s += tanhf(acc[mt][nt][r] + b1[col]) * w2[col];
            }
#pragma unroll
            for (int mask = 1; mask <= 8; mask <<= 1) s += __shfl_xor(s, mask);
            if (l15 == 0 && grow < M) atomicAdd(&bs[grow & 1], s);
        }
    }
    __syncthreads();
    if (tid < 2) partials[((size_t)tl * SEMW_BLOCKS + blockIdx.x) * 2 + tid] = bs[tid];
}

__global__ __launch_bounds__(512) void beta_kernel(const float* __restrict__ partials,
                                                   float* __restrict__ beta2) {
    int t = blockIdx.x;
    const float* p = partials + (size_t)t * SEMW_BLOCKS * 2;
    float s0 = 0.f, s1 = 0.f;
    for (int i = threadIdx.x; i < SEMW_BLOCKS; i += 512) { s0 += p[i * 2]; s1 += p[i * 2 + 1]; }
#pragma unroll
    for (int mask = 1; mask <= 32; mask <<= 1) { s0 += __shfl_xor(s0, mask); s1 += __shfl_xor(s1, mask); }
    __shared__ float w0[8], w1[8];
    int w = threadIdx.x >> 6;
    if ((threadIdx.x & 63) == 0) { w0[w] = s0; w1[w] = s1; }
    __syncthreads();
    if (threadIdx.x == 0) {
        float t0 = 0.f, t1 = 0.f;
        for (int i = 0; i < 8; i++) { t0 += w0[i]; t1 += w1[i]; }
        float m0 = t0 / (float)N_, m1 = t1 / (float)N_;
        float mx = fmaxf(m0, m1);
        float e0 = __expf(m0 - mx), e1 = __expf(m1 - mx);
        float inv = 1.f / (e0 + e1);
        beta2[t * 2] = e0 * inv; beta2[t * 2 + 1] = e1 * inv;
    }
}

// ---------------------------------------------------------------- GAT edge aggregation (batched, 4-edge unroll, ds_swizzle)
__global__ __launch_bounds__(256) void gat_edge_kernel(const unsigned short* __restrict__ R0,
                                                       const int* __restrict__ offsets,
                                                       const int* __restrict__ srcs_sorted,
                                                       const float* __restrict__ gat_attn,
                                                       const float* __restrict__ gat_bias,
                                                       unsigned short* __restrict__ hbuf, int TB) {
    int y = blockIdx.y;
    int r = y & 1, tl = y >> 1;
    const unsigned short* fs = R0 + ((size_t)(2 * r) * TB + tl) * N_ * 128;
    const unsigned short* fd = R0 + ((size_t)(2 * r + 1) * TB + tl) * N_ * 128;
    unsigned short* hout = hbuf + (size_t)tl * N_ * 256;
    const int* offs = offsets + r * (N_ + 1);
    const int* srcs = srcs_sorted + (size_t)r * E_;
    int lane = threadIdx.x & 63;
    int wid = (blockIdx.x * blockDim.x + threadIdx.x) >> 6;
    int nw = (gridDim.x * blockDim.x) >> 6;
    const unsigned short* fs2 = fs + 2 * lane;
    const unsigned short* fd2 = fd + 2 * lane;
    float a0 = gat_attn[r * 128 + 2 * lane], a1 = gat_attn[r * 128 + 2 * lane + 1];
    float b0 = gat_bias[r * 128 + 2 * lane], b1 = gat_bias[r * 128 + 2 * lane + 1];
    for (int n = wid; n < N_; n += nw) {
        unsigned int fdp = *(const unsigned int*)(fd2 + (size_t)n * 128);
        float fd0 = b2f((unsigned short)fdp), fd1 = b2f((unsigned short)(fdp >> 16));
        int e0 = offs[n], e1 = offs[n + 1];
        float den = 0.f, acc0 = 0.f, acc1 = 0.f;
        unsigned int fp[4] = {0u, 0u, 0u, 0u};
#pragma unroll
        for (int j = 0; j < 4; j++)
            if (e0 + j < e1) fp[j] = *(const unsigned int*)(fs2 + (size_t)srcs[e0 + j] * 128);
        for (int e = e0; e < e1; e += 4) {
            unsigned int np[4] = {0u, 0u, 0u, 0u};
#pragma unroll
            for (int j = 0; j < 4; j++)
                if (e + 4 + j < e1) np[j] = *(const unsigned int*)(fs2 + (size_t)srcs[e + 4 + j] * 128);
            float f0[4], f1[4], v[4];
#pragma unroll
            for (int j = 0; j < 4; j++) {
                f0[j] = b2f((unsigned short)fp[j]);
                f1[j] = b2f((unsigned short)(fp[j] >> 16));
                float t0 = f0[j] + fd0; t0 = (t0 > 0.f) ? t0 : 0.2f * t0;
                float t1 = f1[j] + fd1; t1 = (t1 > 0.f) ? t1 : 0.2f * t1;
                v[j] = a0 * t0 + a1 * t1;
            }
            // 16-lane xor-reduce via ds_swizzle (4 independent chains interleave)
#pragma unroll
            for (int j = 0; j < 4; j++)
                v[j] += __int_as_float(__builtin_amdgcn_ds_swizzle(__float_as_int(v[j]), 0x041F));
#pragma unroll
            for (int j = 0; j < 4; j++)
                v[j] += __int_as_float(__builtin_amdgcn_ds_swizzle(__float_as_int(v[j]), 0x081F));
#pragma unroll
            for (int j = 0; j < 4; j++)
                v[j] += __int_as_float(__builtin_amdgcn_ds_swizzle(__float_as_int(v[j]), 0x101F));
#pragma unroll
            for (int j = 0; j < 4; j++)
                v[j] += __int_as_float(__builtin_amdgcn_ds_swizzle(__float_as_int(v[j]), 0x201F));
#pragma unroll
            for (int j = 0; j < 4; j++) {
                float p = (e + j < e1) ? __expf(v[j]) : 0.f;   // logits are O(1): no max needed in fp32
                den += p;
                acc0 = fmaf(p, f0[j], acc0);
                acc1 = fmaf(p, f1[j], acc1);
                fp[j] = np[j];
            }
        }
        float o0, o1;
        if (e1 > e0) { float inv = 1.f / den; o0 = fmaf(acc0, inv, b0); o1 = fmaf(acc1, inv, b1); }
        else { o0 = b0; o1 = b1; }
        unsigned int pk = (unsigned int)f2b(o0) | ((unsigned int)f2b(o1) << 16);
        *(unsigned int*)(hout + (size_t)(n * 2 + r) * 128 + 2 * lane) = pk;
    }
}

// ---------------------------------------------------------------- hsem (batched): beta-mix + relu + bias + relu -> inter
__global__ void hsem_kernel(const unsigned short* __restrict__ hbuf, const float* __restrict__ beta2,
                            const float* __restrict__ h_bias, unsigned short* __restrict__ inter,
                            int tbase) {
    int idx = blockIdx.x * blockDim.x + threadIdx.x;
    if (idx >= N_ * 16) return;
    int tl = blockIdx.y;
    int t = tbase + tl;
    const unsigned short* h = hbuf + (size_t)tl * N_ * 256;
    int n = idx >> 4, c8 = (idx & 15) * 8;
    float b0 = beta2[tl * 2], b1 = beta2[tl * 2 + 1];
    uint4 x0 = *(const uint4*)(h + (size_t)n * 256 + c8);
    uint4 x1 = *(const uint4*)(h + (size_t)n * 256 + 128 + c8);
    const unsigned int* p0 = (const unsigned int*)&x0;
    const unsigned int* p1 = (const unsigned int*)&x1;
    float4 hb0 = *(const float4*)(h_bias + c8);
    float4 hb1 = *(const float4*)(h_bias + c8 + 4);
    float hbv[8] = {hb0.x, hb0.y, hb0.z, hb0.w, hb1.x, hb1.y, hb1.z, hb1.w};
    union { unsigned short s[8]; uint4 u; } o;
#pragma unroll
    for (int i = 0; i < 8; i++) {
        unsigned short s0 = (i & 1) ? (unsigned short)(p0[i >> 1] >> 16) : (unsigned short)p0[i >> 1];
        unsigned short s1 = (i & 1) ? (unsigned short)(p1[i >> 1] >> 16) : (unsigned short)p1[i >> 1];
        float z = fmaxf(fmaxf(b0 * b2f(s0) + b1 * b2f(s1), 0.f) + hbv[i], 0.f);
        o.s[i] = f2b(z);
    }
    *(uint4*)(inter + ((size_t)n * 6 + t) * 128 + c8) = o.u;
}

// ---------------------------------------------------------------- temporal attention + gated residual + LN
__global__ __launch_bounds__(256) void temporal_kernel(const unsigned short* __restrict__ hh,
                                                       const unsigned short* __restrict__ uu,
                                                       const unsigned short* __restrict__ wvv,
                                                       const unsigned short* __restrict__ rv,
                                                       const float* __restrict__ fc_b,
                                                       const float* __restrict__ res_alpha,
                                                       const float* __restrict__ ln_g,
                                                       const float* __restrict__ ln_b,
                                                       float* __restrict__ out, long n0, int nNodes) {
    int lane = threadIdx.x & 63;
    int wid = (blockIdx.x * blockDim.x + threadIdx.x) >> 6;
    if (wid >= nNodes) return;
    long n = n0 + wid;
    size_t base = (size_t)wid * 6 * 128 + 2 * lane;
    float h2[6][2], u2[6][2], wv2[6][2], rv2[6][2];
#pragma unroll
    for (int t = 0; t < 6; t++) {
        unsigned int hp = *(const unsigned int*)(hh + base + t * 128);
        h2[t][0] = b2f((unsigned short)hp); h2[t][1] = b2f((unsigned short)(hp >> 16));
        unsigned int up = *(const unsigned int*)(uu + base + t * 128);
        u2[t][0] = b2f((unsigned short)up); u2[t][1] = b2f((unsigned short)(up >> 16));
        unsigned int wp = *(const unsigned int*)(wvv + base + t * 128);
        wv2[t][0] = b2f((unsigned short)wp); wv2[t][1] = b2f((unsigned short)(wp >> 16));
        unsigned int rp = *(const unsigned int*)(rv + base + t * 128);
        rv2[t][0] = b2f((unsigned short)rp); rv2[t][1] = b2f((unsigned short)(rp >> 16));
    }
    float sc[6][6];
#pragma unroll
    for (int t = 0; t < 6; t++)
#pragma unroll
        for (int s = 0; s < 6; s++)
            sc[t][s] = h2[t][0] * u2[s][0] + h2[t][1] * u2[s][1];
#pragma unroll
    for (int mask = 1; mask <= 32; mask <<= 1)
#pragma unroll
        for (int t = 0; t < 6; t++)
#pragma unroll
            for (int s = 0; s < 6; s++)
                sc[t][s] += __shfl_xor(sc[t][s], mask);

    float a = 1.f / (1.f + __expf(-res_alpha[0]));
    float2 fb = ((const float2*)fc_b)[lane];
    float2 lg = ((const float2*)ln_g)[lane];
    float2 lb = ((const float2*)ln_b)[lane];
#pragma unroll
    for (int t = 0; t < 6; t++) {
        float mx = sc[t][0];
#pragma unroll
        for (int s = 1; s < 6; s++) mx = fmaxf(mx, sc[t][s]);
        float p[6]; float den = 0.f;
#pragma unroll
        for (int s = 0; s < 6; s++) { p[s] = __expf(sc[t][s] - mx); den += p[s]; }
        float inv = 1.f / den;
        float ox = 0.f, oy = 0.f;
#pragma unroll
        for (int s = 0; s < 6; s++) { ox += p[s] * wv2[s][0]; oy += p[s] * wv2[s][1]; }
        ox = fmaxf(ox * inv + fb.x, 0.f);
        oy = fmaxf(oy * inv + fb.y, 0.f);
        ox = ox * a + rv2[t][0] * (1.f - a);
        oy = oy * a + rv2[t][1] * (1.f - a);
        float s1 = ox + oy, s2 = ox * ox + oy * oy;
#pragma unroll
        for (int mask = 1; mask <= 32; mask <<= 1) {
            s1 += __shfl_xor(s1, mask);
            s2 += __shfl_xor(s2, mask);
        }
        float mu = s1 * (1.f / 128.f);
        float var = s2 * (1.f / 128.f) - mu * mu;
        float rs = rsqrtf(var + 1e-5f);
        float2 o;
        o.x = (ox - mu) * rs * lg.x + lb.x;
        o.y = (oy - mu) * rs * lg.y + lb.y;
        ((float2*)(out + ((size_t)t * N_ + n) * 128))[lane] = o;
    }
}

// ---------------------------------------------------------------- launch
extern "C" void kernel_launch(void* const* d_in, const int* in_sizes, int n_in,
                              void* d_out, int out_size, void* d_ws, size_t ws_size,
                              hipStream_t stream) {
    const float* x        = (const float*)d_in[0];
    const int*   src      = (const int*)d_in[1];
    const int*   dst      = (const int*)d_in[2];
    const float* gat_wsrc = (const float*)d_in[3];
    const float* gat_wdst = (const float*)d_in[4];
    const float* gat_attn = (const float*)d_in[5];
    const float* gat_bias = (const float*)d_in[6];
    const float* h_bias   = (const float*)d_in[7];
    const float* sem_w1   = (const float*)d_in[8];
    const float* sem_b1   = (const float*)d_in[9];
    const float* sem_w2   = (const float*)d_in[10];
    const float* proj_w   = (const float*)d_in[11];
    const float* proj_b   = (const float*)d_in[12];
    const float* qw       = (const float*)d_in[13];
    const float* kw       = (const float*)d_in[14];
    const float* vw       = (const float*)d_in[15];
    const float* fc_w     = (const float*)d_in[16];
    const float* fc_b     = (const float*)d_in[17];
    const float* res_w    = (const float*)d_in[18];
    const float* res_b    = (const float*)d_in[19];
    const float* res_alpha= (const float*)d_in[20];
    const float* ln_g     = (const float*)d_in[21];
    const float* ln_b     = (const float*)d_in[22];
    (void)in_sizes; (void)n_in; (void)out_size;

    // adaptive batching: full-T batch needs ~470 MB of ws
    int TB = (ws_size >= (size_t)500 * 1024 * 1024) ? 6 : 2;
    int CH = (TB == 6) ? N_ : 12500;

    char* ws = (char*)d_ws;
    size_t off = 0;
    auto alloc = [&](size_t bytes) -> void* {
        void* p = ws + off;
        off += (bytes + 255) & ~(size_t)255;
        return p;
    };
    int*   counts      = (int*)alloc((size_t)R_ * N_ * 4);
    int*   offsets     = (int*)alloc((size_t)R_ * (N_ + 1) * 4);
    int*   cursor      = (int*)alloc((size_t)R_ * N_ * 4);
    int*   srcs_sorted = (int*)alloc((size_t)R_ * E_ * 4);
    float* pe          = (float*)alloc(T_ * NH_ * 4);
    float* partials    = (float*)alloc((size_t)T_ * SEMW_BLOCKS * 2 * 4);
    float* beta2       = (float*)alloc(T_ * 2 * 4);
    float* Mu          = (float*)alloc(16384 * 4);
    float* Mwv         = (float*)alloc(16384 * 4);
    float* cbuf        = (float*)alloc(4 * 768 * 4);
    unsigned short* wt_gs0  = (unsigned short*)alloc(16384 * 2);
    unsigned short* wt_gs1  = (unsigned short*)alloc(16384 * 2);
    unsigned short* wt_gd0  = (unsigned short*)alloc(16384 * 2);
    unsigned short* wt_gd1  = (unsigned short*)alloc(16384 * 2);
    unsigned short* wt_sem  = (unsigned short*)alloc(16384 * 2);
    unsigned short* wt_res  = (unsigned short*)alloc(16384 * 2);
    unsigned short* wt_hh   = (unsigned short*)alloc(16384 * 2);
    unsigned short* wt_pu   = (unsigned short*)alloc(16384 * 2);
    unsigned short* wt_pwv  = (unsigned short*)alloc(16384 * 2);
    unsigned short* xb      = (unsigned short*)alloc((size_t)T_ * N_ * 128 * 2);   // 76.8 MB
    unsigned short* inter   = (unsigned short*)alloc((size_t)N_ * T_ * 128 * 2);   // 76.8 MB
    size_t Rgat = (size_t)4 * TB * N_ * 128 * 2;
    size_t Rtmp = (size_t)4 * CH * 6 * 128 * 2;
    unsigned short* R0      = (unsigned short*)alloc(Rgat > Rtmp ? Rgat : Rtmp);

    unsigned short* hbuf = (unsigned short*)d_out;   // TB*N*256 bf16 <= 153.6 MB; overwritten by temporal phase

    // --- CSR + precomputes
    hipMemsetAsync(counts, 0, (size_t)R_ * N_ * 4, stream);
    hist_kernel<<<(R_ * E_ + 255) / 256, 256, 0, stream>>>(dst, counts);
    scan_kernel<<<R_, 1024, 0, stream>>>(counts, offsets, cursor);
    scatter_kernel<<<(R_ * E_ + 255) / 256, 256, 0, stream>>>(src, dst, cursor, srcs_sorted);
    pe_kernel<<<1, 128, 0, stream>>>(pe);
    cvt_x_kernel<<<18750, 256, 0, stream>>>(x, xb, (long)T_ * N_ * 128);
    CvtArgs ca;
    ca.s[0] = gat_wsrc;         ca.d[0] = wt_gs0;
    ca.s[1] = gat_wsrc + 16384; ca.d[1] = wt_gs1;
    ca.s[2] = gat_wdst;         ca.d[2] = wt_gd0;
    ca.s[3] = gat_wdst + 16384; ca.d[3] = wt_gd1;
    ca.s[4] = sem_w1;           ca.d[4] = wt_sem;
    ca.s[5] = res_w;            ca.d[5] = wt_res;
    cvt_wt_kernel<<<dim3(128, 6), 128, 0, stream>>>(ca);
    build_m_kernel<<<dim3(128, 2), 128, 0, stream>>>(qw, kw, vw, fc_w, Mu, Mwv);
    fold_w_kernel<<<dim3(128, 3), 128, 0, stream>>>(proj_w, Mu, Mwv, wt_hh, wt_pu, wt_pwv);
    fold_c_kernel<<<6, 128, 0, stream>>>(proj_b, pe, Mu, Mwv, res_b, cbuf);

    // --- GAT phase, batched over TB timesteps per group
    size_t TBN = (size_t)TB * N_ * 128;
    for (int tg = 0; tg < T_ / TB; tg++) {
        int tbase = tg * TB;
        MArgs ga{};
        ga.A = xb + (size_t)tbase * N_ * 128;
        ga.row0 = 0; ga.M = TB * N_;
        ga.W0 = wt_gs0; ga.C0 = R0;                 // fs r0 [tl][n]
        ga.W1 = wt_gd0; ga.C1 = R0 + TBN;           // fd r0
        ga.W2 = wt_gs1; ga.C2 = R0 + 2 * TBN;       // fs r1
        ga.W3 = wt_gd1; ga.C3 = R0 + 3 * TBN;       // fd r1
        mgemm_kernel<0><<<dim3((TB * N_ + 127) / 128, 4), 256, 0, stream>>>(ga);

        gat_edge_kernel<<<dim3(1024, 2 * TB), 256, 0, stream>>>(R0, offsets, srcs_sorted,
                                                                gat_attn, gat_bias, hbuf, TB);

        semw_kernel<<<dim3(SEMW_BLOCKS, TB), 256, 0, stream>>>(hbuf, wt_sem, sem_b1, sem_w2,
                                                               partials + (size_t)tbase * SEMW_BLOCKS * 2);
        beta_kernel<<<TB, 512, 0, stream>>>(partials + (size_t)tbase * SEMW_BLOCKS * 2,
                                            beta2 + tbase * 2);
        hsem_kernel<<<dim3((N_ * 16 + 255) / 256, TB), 256, 0, stream>>>(hbuf, beta2 + tbase * 2,
                                                                         h_bias, inter, tbase);
    }

    // --- temporal attention + residual + LN (batched; overwrites d_out)
    for (int c = 0; c < N_ / CH; c++) {
        long n0 = (long)c * CH;
        long r0 = n0 * 6;
        int Mc = CH * 6;
        int nb = (Mc + 127) / 128;
        size_t MB = (size_t)Mc * 128;

        MArgs gt{};
        gt.A = inter + (size_t)r0 * 128;
        gt.Axb = xb;
        gt.row0 = r0; gt.M = Mc; gt.cb = cbuf;
        gt.W0 = wt_hh;  gt.C0 = R0;
        gt.W1 = wt_pu;  gt.C1 = R0 + MB;
        gt.W2 = wt_pwv; gt.C2 = R0 + 2 * MB;
        gt.W3 = wt_res; gt.C3 = R0 + 3 * MB;
        mgemm_kernel<3><<<dim3(nb, 4), 256, 0, stream>>>(gt);

        temporal_kernel<<<(CH + 3) / 4, 256, 0, stream>>>(R0, R0 + MB, R0 + 2 * MB, R0 + 3 * MB,
                                                          fc_b, res_alpha, ln_g, ln_b,
                                                          (float*)d_out, n0, CH);
    }
}

// Round 6
// 1424.899 us; speedup vs baseline: 2.3218x; 1.2424x over previous
//
#include <hip/hip_runtime.h>
#include <math.h>

#define T_  6
#define N_  50000
#define NH_ 128
#define R_  2
#define E_  800000
#define SEMW_BLOCKS ((2*N_ + 127)/128)   // 782

typedef __attribute__((ext_vector_type(8))) short bf16x8;
typedef __attribute__((ext_vector_type(4))) float f32x4;

__device__ inline unsigned short f2b(float f) {
    union { float f; unsigned int u; } v; v.f = f;
    unsigned int u = v.u;
    unsigned int r = (u + 0x7FFFu + ((u >> 16) & 1u)) >> 16;
    return (unsigned short)r;
}
__device__ inline float b2f(unsigned short h) {
    union { unsigned int u; float f; } v; v.u = ((unsigned int)h) << 16;
    return v.f;
}

// ---------------------------------------------------------------- CSR build
__global__ void hist_kernel(const int* __restrict__ dst, int* __restrict__ counts) {
    int j = blockIdx.x * blockDim.x + threadIdx.x;
    if (j < R_ * E_) atomicAdd(&counts[(j / E_) * N_ + dst[j]], 1);
}

__global__ __launch_bounds__(1024) void scan_kernel(const int* __restrict__ counts,
                                                    int* __restrict__ offsets,
                                                    int* __restrict__ cursor) {
    int r = blockIdx.x;
    __shared__ int sm[1024];
    __shared__ int carry;
    if (threadIdx.x == 0) carry = 0;
    __syncthreads();
    for (int base = 0; base < N_; base += 1024) {
        int i = base + threadIdx.x;
        int v = (i < N_) ? counts[r * N_ + i] : 0;
        sm[threadIdx.x] = v;
        __syncthreads();
        for (int off = 1; off < 1024; off <<= 1) {
            int t = 0;
            if (threadIdx.x >= off) t = sm[threadIdx.x - off];
            __syncthreads();
            sm[threadIdx.x] += t;
            __syncthreads();
        }
        int incl = sm[threadIdx.x];
        int run = carry;
        int excl = run + incl - v;
        if (i < N_) { offsets[r * (N_ + 1) + i] = excl; cursor[r * N_ + i] = excl; }
        __syncthreads();
        if (threadIdx.x == 1023) carry = run + incl;
        __syncthreads();
    }
    if (threadIdx.x == 0) offsets[r * (N_ + 1) + N_] = carry;
}

__global__ void scatter_kernel(const int* __restrict__ src, const int* __restrict__ dst,
                               int* __restrict__ cursor, int* __restrict__ srcs_sorted) {
    int j = blockIdx.x * blockDim.x + threadIdx.x;
    if (j < R_ * E_) {
        int r = j / E_;
        int pos = atomicAdd(&cursor[r * N_ + dst[j]], 1);
        srcs_sorted[(size_t)r * E_ + pos] = src[j];
    }
}

// ---------------------------------------------------------------- small precomputes
__global__ void pe_kernel(float* __restrict__ pe) {
    int c = threadIdx.x;
    int k = c & ~1;
    double div = exp((double)k * (-log(100000.0) / 128.0));
    for (int t = 0; t < T_; t++) {
        double pos = (double)(t + 1);
        double v = (c & 1) ? cos(pos * div) : sin(pos * div);
        pe[t * NH_ + c] = (float)v;
    }
}

__global__ void cvt_x_kernel(const float* __restrict__ in, unsigned short* __restrict__ out, long n) {
    long i = ((long)blockIdx.x * blockDim.x + threadIdx.x) * 8;
    if (i >= n) return;
    float4 a = *(const float4*)(in + i);
    float4 b = *(const float4*)(in + i + 4);
    union { unsigned short s[8]; uint4 u; } o;
    o.s[0] = f2b(a.x); o.s[1] = f2b(a.y); o.s[2] = f2b(a.z); o.s[3] = f2b(a.w);
    o.s[4] = f2b(b.x); o.s[5] = f2b(b.y); o.s[6] = f2b(b.z); o.s[7] = f2b(b.w);
    *(uint4*)(out + i) = o.u;
}

// transpose+convert 128x128 weights into Wt[n][k] bf16
struct CvtArgs {
    const float* s[6];
    unsigned short* d[6];
};
__global__ void cvt_wt_kernel(CvtArgs a) {
    int y = blockIdx.y, n = blockIdx.x, k = threadIdx.x;
    a.d[y][n * 128 + k] = f2b(a.s[y][k * 128 + n]);
}

// Mu[c][f] = sum_d kw[f][d]*qw[c][d];  Mwv[c][e] = sum_d vw[e][d]*fcw[d][c]
__global__ void build_m_kernel(const float* __restrict__ qw, const float* __restrict__ kw,
                               const float* __restrict__ vw, const float* __restrict__ fcw,
                               float* __restrict__ Mu, float* __restrict__ Mwv) {
    int y = blockIdx.y, c = blockIdx.x, f = threadIdx.x;
    float s = 0.f;
    if (y == 0) {
        for (int d = 0; d < 128; d++) s += kw[f * 128 + d] * qw[c * 128 + d];
        Mu[c * 128 + f] = s;
    } else {
        for (int d = 0; d < 128; d++) s += vw[f * 128 + d] * fcw[d * 128 + c];
        Mwv[c * 128 + f] = s;
    }
}

__global__ void fold_w_kernel(const float* __restrict__ proj, const float* __restrict__ Mu,
                              const float* __restrict__ Mwv, unsigned short* __restrict__ wt_hh,
                              unsigned short* __restrict__ wt_pu, unsigned short* __restrict__ wt_pwv) {
    int y = blockIdx.y, c = blockIdx.x, k = threadIdx.x;
    if (y == 0) { wt_hh[c * 128 + k] = f2b(proj[k * 128 + c]); return; }
    const float* M = (y == 1) ? Mu : Mwv;
    float s = 0.f;
    for (int f = 0; f < 128; f++) s += proj[k * 128 + f] * M[c * 128 + f];
    ((y == 1) ? wt_pu : wt_pwv)[c * 128 + k] = f2b(s);
}

// cbuf[4][6][128]
__global__ void fold_c_kernel(const float* __restrict__ proj_b, const float* __restrict__ pe,
                              const float* __restrict__ Mu, const float* __restrict__ Mwv,
                              const float* __restrict__ res_b, float* __restrict__ cbuf) {
    int t = blockIdx.x, c = threadIdx.x;
    cbuf[0 * 768 + t * 128 + c] = proj_b[c] + pe[t * 128 + c];
    float s1 = 0.f, s2 = 0.f;
    for (int f = 0; f < 128; f++) {
        float b = proj_b[f] + pe[t * 128 + f];
        s1 += b * Mu[c * 128 + f];
        s2 += b * Mwv[c * 128 + f];
    }
    cbuf[1 * 768 + t * 128 + c] = s1;
    cbuf[2 * 768 + t * 128 + c] = s2;
    cbuf[3 * 768 + t * 128 + c] = res_b[c];
}

// ---------------------------------------------------------------- MFMA GEMM, 4 fused outputs sharing the staged A-tile
struct MArgs {
    const unsigned short* A;     // shared A (y0..y3 for EPI0; y0..y2 for EPI3)
    const unsigned short* Axb;   // EPI3 y3: x in [t][n] layout (mode-1 addressing)
    const unsigned short* W0; const unsigned short* W1;
    const unsigned short* W2; const unsigned short* W3;
    unsigned short* C0; unsigned short* C1; unsigned short* C2; unsigned short* C3;
    const float* cb;             // [4][6][128] (EPI 3)
    long row0;
    int  M;
};

// EPI: 0 = bf16 out; 3 = + cb[y][t6][col]
template <int EPI>
__global__ __launch_bounds__(256) void mgemm_kernel(MArgs g) {
    __shared__ __align__(16) char As[128 * 256];
    __shared__ __align__(16) char Bs[128 * 256];
    int tid = threadIdx.x;
    int brow0 = blockIdx.x * 128;
    const unsigned short* Ws[4] = {g.W0, g.W1, g.W2, g.W3};
    unsigned short* Cs[4] = {g.C0, g.C1, g.C2, g.C3};

    auto stageA = [&](const unsigned short* Abase, bool m1) {
#pragma unroll
        for (int i = 0; i < 8; i++) {
            int c = tid + i * 256;
            int row = c >> 4;
            int cb = (c & 15) << 4;
            int scb = cb ^ ((row & 7) << 4);
            int grow = brow0 + row;
            float4 av = make_float4(0.f, 0.f, 0.f, 0.f);
            if (grow < g.M) {
                long ar;
                if (!m1) ar = grow;
                else { long gg = g.row0 + grow; long n = gg / 6, t = gg - n * 6; ar = t * (long)N_ + n; }
                av = *(const float4*)((const char*)Abase + ar * 256 + cb);
            }
            *(float4*)(As + row * 256 + scb) = av;
        }
    };
    auto stageB = [&](const unsigned short* W) {
#pragma unroll
        for (int i = 0; i < 8; i++) {
            int c = tid + i * 256;
            int row = c >> 4;
            int cb = (c & 15) << 4;
            int scb = cb ^ ((row & 7) << 4);
            *(float4*)(Bs + row * 256 + scb) = *(const float4*)((const char*)W + (size_t)row * 256 + cb);
        }
    };

    int w = tid >> 6, l = tid & 63;
    int l15 = l & 15, lg = l >> 4;

    stageA(g.A, false);
    for (int y = 0; y < 4; y++) {
        if (y > 0) __syncthreads();               // previous compute done reading LDS
        if (EPI == 3 && y == 3) stageA(g.Axb, true);
        stageB(Ws[y]);
        __syncthreads();

        f32x4 acc[2][8];
#pragma unroll
        for (int a = 0; a < 2; a++)
#pragma unroll
            for (int b = 0; b < 8; b++) acc[a][b] = (f32x4)(0.f);
#pragma unroll
        for (int ks = 0; ks < 4; ks++) {
            bf16x8 bf[8];
#pragma unroll
            for (int nt = 0; nt < 8; nt++) {
                int rn = nt * 16 + l15;
                int cbyte = (ks * 64 + lg * 16) ^ ((rn & 7) << 4);
                bf[nt] = *(const bf16x8*)(Bs + rn * 256 + cbyte);
            }
#pragma unroll
            for (int mt = 0; mt < 2; mt++) {
                int rm = w * 32 + mt * 16 + l15;
                int cbyte = (ks * 64 + lg * 16) ^ ((rm & 7) << 4);
                bf16x8 af = *(const bf16x8*)(As + rm * 256 + cbyte);
#pragma unroll
                for (int nt = 0; nt < 8; nt++)
                    acc[mt][nt] = __builtin_amdgcn_mfma_f32_16x16x32_bf16(af, bf[nt], acc[mt][nt], 0, 0, 0);
            }
        }
        unsigned short* C = Cs[y];
#pragma unroll
        for (int mt = 0; mt < 2; mt++) {
#pragma unroll
            for (int r = 0; r < 4; r++) {
                int row = w * 32 + mt * 16 + lg * 4 + r;
                int grow = brow0 + row;
                if (grow >= g.M) continue;
                long t6 = 0;
                if (EPI == 3) t6 = (g.row0 + grow) % 6;
#pragma unroll
                for (int nt = 0; nt < 8; nt++) {
                    int col = nt * 16 + l15;
                    float v = acc[mt][nt][r];
                    if (EPI == 3) v += g.cb[y * 768 + t6 * 128 + col];
                    C[(size_t)grow * 128 + col] = f2b(v);
                }
            }
        }
    }
}

// ---------------------------------------------------------------- semantic w partials (batched over t via blockIdx.y)
__global__ __launch_bounds__(256) void semw_kernel(const unsigned short* __restrict__ Abase,
                                                   const unsigned short* __restrict__ Wt,
                                                   const float* __restrict__ b1,
                                                   const float* __restrict__ w2,
                                                   float* __restrict__ partials) {
    __shared__ __align__(16) char As[128 * 256];
    __shared__ __align__(16) char Bs[128 * 256];
    __shared__ float bs[2];
    int tid = threadIdx.x;
    if (tid < 2) bs[tid] = 0.f;
    int tl = blockIdx.y;
    const unsigned short* A = Abase + (size_t)tl * N_ * 256;
    const int M = 2 * N_;
    int brow0 = blockIdx.x * 128;
#pragma unroll
    for (int i = 0; i < 8; i++) {
        int c = tid + i * 256;
        int row = c >> 4;
        int cb = (c & 15) << 4;
        int scb = cb ^ ((row & 7) << 4);
        *(float4*)(Bs + row * 256 + scb) = *(const float4*)((const char*)Wt + (size_t)row * 256 + cb);
        int grow = brow0 + row;
        float4 av = make_float4(0.f, 0.f, 0.f, 0.f);
        if (grow < M) av = *(const float4*)((const char*)A + (size_t)grow * 256 + cb);
        *(float4*)(As + row * 256 + scb) = av;
    }
    __syncthreads();
    int w = tid >> 6, l = tid & 63;
    int l15 = l & 15, lg = l >> 4;
    f32x4 acc[2][8];
#pragma unroll
    for (int a = 0; a < 2; a++)
#pragma unroll
        for (int b = 0; b < 8; b++) acc[a][b] = (f32x4)(0.f);
#pragma unroll
    for (int ks = 0; ks < 4; ks++) {
        bf16x8 bf[8];
#pragma unroll
        for (int nt = 0; nt < 8; nt++) {
            int rn = nt * 16 + l15;
            int cbyte = (ks * 64 + lg * 16) ^ ((rn & 7) << 4);
            bf[nt] = *(const bf16x8*)(Bs + rn * 256 + cbyte);
        }
#pragma unroll
        for (int mt = 0; mt < 2; mt++) {
            int rm = w * 32 + mt * 16 + l15;
            int cbyte = (ks * 64 + lg * 16) ^ ((rm & 7) << 4);
            bf16x8 af = *(const bf16x8*)(As + rm * 256 + cbyte);
#pragma unroll
            for (int nt = 0; nt < 8; nt++)
                acc[mt][nt] = __builtin_amdgcn_mfma_f32_16x16x32_bf16(af, bf[nt], acc[mt][nt], 0, 0, 0);
        }
    }
#pragma unroll
    for (int mt = 0; mt < 2; mt++) {
#pragma unroll
        for (int r = 0; r < 4; r++) {
            int row = w * 32 + mt * 16 + lg * 4 + r;
            int grow = brow0 + row;
            float s = 0.f;
#pragma unroll
            for (int nt = 0; nt < 8; nt++) {
                int col = nt * 16 + l15;
                s += tanhf(acc[mt][nt][r] + b1[col]) * w2[col];
            }
#pragma unroll
            for (int mask = 1; mask <= 8; mask <<= 1) s += __shfl_xor(s, mask);
            if (l15 == 0 && grow < M) atomicAdd(&bs[grow & 1], s);
        }
    }
    __syncthreads();
    if (tid < 2) partials[((size_t)tl * SEMW_BLOCKS + blockIdx.x) * 2 + tid] = bs[tid];
}

__global__ __launch_bounds__(512) void beta_kernel(const float* __restrict__ partials,
                                                   float* __restrict__ beta2) {
    int t = blockIdx.x;
    const float* p = partials + (size_t)t * SEMW_BLOCKS * 2;
    float s0 = 0.f, s1 = 0.f;
    for (int i = threadIdx.x; i < SEMW_BLOCKS; i += 512) { s0 += p[i * 2]; s1 += p[i * 2 + 1]; }
#pragma unroll
    for (int mask = 1; mask <= 32; mask <<= 1) { s0 += __shfl_xor(s0, mask); s1 += __shfl_xor(s1, mask); }
    __shared__ float w0[8], w1[8];
    int w = threadIdx.x >> 6;
    if ((threadIdx.x & 63) == 0) { w0[w] = s0; w1[w] = s1; }
    __syncthreads();
    if (threadIdx.x == 0) {
        float t0 = 0.f, t1 = 0.f;
        for (int i = 0; i < 8; i++) { t0 += w0[i]; t1 += w1[i]; }
        float m0 = t0 / (float)N_, m1 = t1 / (float)N_;
        float mx = fmaxf(m0, m1);
        float e0 = __expf(m0 - mx), e1 = __expf(m1 - mx);
        float inv = 1.f / (e0 + e1);
        beta2[t * 2] = e0 * inv; beta2[t * 2 + 1] = e1 * inv;
    }
}

// ---------------------------------------------------------------- GAT edge aggregation: 4 nodes/wave, 16 lanes/node, 8 ch/lane
__global__ __launch_bounds__(256) void gat_edge_kernel(const unsigned short* __restrict__ R0,
                                                       const int* __restrict__ offsets,
                                                       const int* __restrict__ srcs_sorted,
                                                       const float* __restrict__ gat_attn,
                                                       const float* __restrict__ gat_bias,
                                                       unsigned short* __restrict__ hbuf, int TB) {
    int y = blockIdx.y;
    int r = y & 1, tl = y >> 1;
    const unsigned short* fs = R0 + ((size_t)(2 * r) * TB + tl) * N_ * 128;
    const unsigned short* fd = R0 + ((size_t)(2 * r + 1) * TB + tl) * N_ * 128;
    unsigned short* hout = hbuf + (size_t)tl * N_ * 256;
    const int* offs = offsets + r * (N_ + 1);
    const int* srcs = srcs_sorted + (size_t)r * E_;
    int lane = threadIdx.x & 63;
    int q = lane >> 4, l16 = lane & 15;
    int c0 = l16 * 8;
    int wid = (blockIdx.x * blockDim.x + threadIdx.x) >> 6;
    int nw = (gridDim.x * blockDim.x) >> 6;
    float4 a0 = *(const float4*)(gat_attn + r * 128 + c0);
    float4 a1 = *(const float4*)(gat_attn + r * 128 + c0 + 4);
    float av[8] = {a0.x, a0.y, a0.z, a0.w, a1.x, a1.y, a1.z, a1.w};
    float4 bb0 = *(const float4*)(gat_bias + r * 128 + c0);
    float4 bb1 = *(const float4*)(gat_bias + r * 128 + c0 + 4);
    float bv[8] = {bb0.x, bb0.y, bb0.z, bb0.w, bb1.x, bb1.y, bb1.z, bb1.w};

    for (int gidx = wid; gidx < N_ / 4; gidx += nw) {
        int n = gidx * 4 + q;
        uint4 fdp = *(const uint4*)(fd + (size_t)n * 128 + c0);
        const unsigned int* fdu = (const unsigned int*)&fdp;
        float fdv[8];
#pragma unroll
        for (int j = 0; j < 8; j++)
            fdv[j] = (j & 1) ? b2f((unsigned short)(fdu[j >> 1] >> 16)) : b2f((unsigned short)fdu[j >> 1]);
        int e0 = offs[n], e1 = offs[n + 1];
        int deg = e1 - e0;
        int m = deg;
        m = max(m, __shfl_xor(m, 16));
        m = max(m, __shfl_xor(m, 32));
        float den = 0.f;
        float acc[8];
#pragma unroll
        for (int j = 0; j < 8; j++) acc[j] = 0.f;

        uint4 fp = make_uint4(0, 0, 0, 0);
        if (deg > 0) fp = *(const uint4*)(fs + (size_t)srcs[e0] * 128 + c0);
        for (int i = 0; i < m; i++) {
            uint4 nxt = make_uint4(0, 0, 0, 0);
            if (i + 1 < deg) nxt = *(const uint4*)(fs + (size_t)srcs[e0 + i + 1] * 128 + c0);
            const unsigned int* fu = (const unsigned int*)&fp;
            float f[8];
            float v = 0.f;
#pragma unroll
            for (int j = 0; j < 8; j++) {
                f[j] = (j & 1) ? b2f((unsigned short)(fu[j >> 1] >> 16)) : b2f((unsigned short)fu[j >> 1]);
                float t = f[j] + fdv[j];
                float lr = fmaf(0.2f, fminf(t, 0.f), fmaxf(t, 0.f));
                v = fmaf(av[j], lr, v);
            }
            // per-head (4-lane cluster) sum
            v += __int_as_float(__builtin_amdgcn_ds_swizzle(__float_as_int(v), 0x041F));
            v += __int_as_float(__builtin_amdgcn_ds_swizzle(__float_as_int(v), 0x081F));
            float p = (i < deg) ? __expf(v) : 0.f;   // logits O(1): no max subtraction needed
            den += p;
#pragma unroll
            for (int j = 0; j < 8; j++) acc[j] = fmaf(p, f[j], acc[j]);
            fp = nxt;
        }
        float inv = (deg > 0) ? 1.f / den : 0.f;
        union { unsigned short s[8]; uint4 u; } o;
#pragma unroll
        for (int j = 0; j < 8; j++) o.s[j] = f2b(fmaf(acc[j], inv, bv[j]));
        *(uint4*)(hout + (size_t)(n * 2 + r) * 128 + c0) = o.u;
    }
}

// ---------------------------------------------------------------- hsem (batched)
__global__ void hsem_kernel(const unsigned short* __restrict__ hbuf, const float* __restrict__ beta2,
                            const float* __restrict__ h_bias, unsigned short* __restrict__ inter,
                            int tbase) {
    int idx = blockIdx.x * blockDim.x + threadIdx.x;
    if (idx >= N_ * 16) return;
    int tl = blockIdx.y;
    int t = tbase + tl;
    const unsigned short* h = hbuf + (size_t)tl * N_ * 256;
    int n = idx >> 4, c8 = (idx & 15) * 8;
    float b0 = beta2[tl * 2], b1 = beta2[tl * 2 + 1];
    uint4 x0 = *(const uint4*)(h + (size_t)n * 256 + c8);
    uint4 x1 = *(const uint4*)(h + (size_t)n * 256 + 128 + c8);
    const unsigned int* p0 = (const unsigned int*)&x0;
    const unsigned int* p1 = (const unsigned int*)&x1;
    float4 hb0 = *(const float4*)(h_bias + c8);
    float4 hb1 = *(const float4*)(h_bias + c8 + 4);
    float hbv[8] = {hb0.x, hb0.y, hb0.z, hb0.w, hb1.x, hb1.y, hb1.z, hb1.w};
    union { unsigned short s[8]; uint4 u; } o;
#pragma unroll
    for (int i = 0; i < 8; i++) {
        unsigned short s0 = (i & 1) ? (unsigned short)(p0[i >> 1] >> 16) : (unsigned short)p0[i >> 1];
        unsigned short s1 = (i & 1) ? (unsigned short)(p1[i >> 1] >> 16) : (unsigned short)p1[i >> 1];
        float z = fmaxf(fmaxf(b0 * b2f(s0) + b1 * b2f(s1), 0.f) + hbv[i], 0.f);
        o.s[i] = f2b(z);
    }
    *(uint4*)(inter + ((size_t)n * 6 + t) * 128 + c8) = o.u;
}

// ---------------------------------------------------------------- temporal attention + gated residual + LN
__global__ __launch_bounds__(256) void temporal_kernel(const unsigned short* __restrict__ hh,
                                                       const unsigned short* __restrict__ uu,
                                                       const unsigned short* __restrict__ wvv,
                                                       const unsigned short* __restrict__ rv,
                                                       const float* __restrict__ fc_b,
                                                       const float* __restrict__ res_alpha,
                                                       const float* __restrict__ ln_g,
                                                       const float* __restrict__ ln_b,
                                                       float* __restrict__ out, long n0, int nNodes) {
    int lane = threadIdx.x & 63;
    int wid = (blockIdx.x * blockDim.x + threadIdx.x) >> 6;
    if (wid >= nNodes) return;
    long n = n0 + wid;
    size_t base = (size_t)wid * 6 * 128 + 2 * lane;
    float h2[6][2], u2[6][2], wv2[6][2], rv2[6][2];
#pragma unroll
    for (int t = 0; t < 6; t++) {
        unsigned int hp = *(const unsigned int*)(hh + base + t * 128);
        h2[t][0] = b2f((unsigned short)hp); h2[t][1] = b2f((unsigned short)(hp >> 16));
        unsigned int up = *(const unsigned int*)(uu + base + t * 128);
        u2[t][0] = b2f((unsigned short)up); u2[t][1] = b2f((unsigned short)(up >> 16));
        unsigned int wp = *(const unsigned int*)(wvv + base + t * 128);
        wv2[t][0] = b2f((unsigned short)wp); wv2[t][1] = b2f((unsigned short)(wp >> 16));
        unsigned int rp = *(const unsigned int*)(rv + base + t * 128);
        rv2[t][0] = b2f((unsigned short)rp); rv2[t][1] = b2f((unsigned short)(rp >> 16));
    }
    float sc[6][6];
#pragma unroll
    for (int t = 0; t < 6; t++)
#pragma unroll
        for (int s = 0; s < 6; s++)
            sc[t][s] = h2[t][0] * u2[s][0] + h2[t][1] * u2[s][1];
#pragma unroll
    for (int mask = 1; mask <= 32; mask <<= 1)
#pragma unroll
        for (int t = 0; t < 6; t++)
#pragma unroll
            for (int s = 0; s < 6; s++)
                sc[t][s] += __shfl_xor(sc[t][s], mask);

    float a = 1.f / (1.f + __expf(-res_alpha[0]));
    float2 fb = ((const float2*)fc_b)[lane];
    float2 lg = ((const float2*)ln_g)[lane];
    float2 lb = ((const float2*)ln_b)[lane];
#pragma unroll
    for (int t = 0; t < 6; t++) {
        float mx = sc[t][0];
#pragma unroll
        for (int s = 1; s < 6; s++) mx = fmaxf(mx, sc[t][s]);
        float p[6]; float den = 0.f;
#pragma unroll
        for (int s = 0; s < 6; s++) { p[s] = __expf(sc[t][s] - mx); den += p[s]; }
        float inv = 1.f / den;
        float ox = 0.f, oy = 0.f;
#pragma unroll
        for (int s = 0; s < 6; s++) { ox += p[s] * wv2[s][0]; oy += p[s] * wv2[s][1]; }
        ox = fmaxf(ox * inv + fb.x, 0.f);
        oy = fmaxf(oy * inv + fb.y, 0.f);
        ox = ox * a + rv2[t][0] * (1.f - a);
        oy = oy * a + rv2[t][1] * (1.f - a);
        float s1 = ox + oy, s2 = ox * ox + oy * oy;
#pragma unroll
        for (int mask = 1; mask <= 32; mask <<= 1) {
            s1 += __shfl_xor(s1, mask);
            s2 += __shfl_xor(s2, mask);
        }
        float mu = s1 * (1.f / 128.f);
        float var = s2 * (1.f / 128.f) - mu * mu;
        float rs = rsqrtf(var + 1e-5f);
        float2 o;
        o.x = (ox - mu) * rs * lg.x + lb.x;
        o.y = (oy - mu) * rs * lg.y + lb.y;
        ((float2*)(out + ((size_t)t * N_ + n) * 128))[lane] = o;
    }
}

// ---------------------------------------------------------------- launch
extern "C" void kernel_launch(void* const* d_in, const int* in_sizes, int n_in,
                              void* d_out, int out_size, void* d_ws, size_t ws_size,
                              hipStream_t stream) {
    const float* x        = (const float*)d_in[0];
    const int*   src      = (const int*)d_in[1];
    const int*   dst      = (const int*)d_in[2];
    const float* gat_wsrc = (const float*)d_in[3];
    const float* gat_wdst = (const float*)d_in[4];
    const float* gat_attn = (const float*)d_in[5];
    const float* gat_bias = (const float*)d_in[6];
    const float* h_bias   = (const float*)d_in[7];
    const float* sem_w1   = (const float*)d_in[8];
    const float* sem_b1   = (const float*)d_in[9];
    const float* sem_w2   = (const float*)d_in[10];
    const float* proj_w   = (const float*)d_in[11];
    const float* proj_b   = (const float*)d_in[12];
    const float* qw       = (const float*)d_in[13];
    const float* kw       = (const float*)d_in[14];
    const float* vw       = (const float*)d_in[15];
    const float* fc_w     = (const float*)d_in[16];
    const float* fc_b     = (const float*)d_in[17];
    const float* res_w    = (const float*)d_in[18];
    const float* res_b    = (const float*)d_in[19];
    const float* res_alpha= (const float*)d_in[20];
    const float* ln_g     = (const float*)d_in[21];
    const float* ln_b     = (const float*)d_in[22];
    (void)in_sizes; (void)n_in; (void)out_size;

    int TB = (ws_size >= (size_t)500 * 1024 * 1024) ? 6 : 2;
    int CH = (TB == 6) ? N_ : 12500;

    char* ws = (char*)d_ws;
    size_t off = 0;
    auto alloc = [&](size_t bytes) -> void* {
        void* p = ws + off;
        off += (bytes + 255) & ~(size_t)255;
        return p;
    };
    int*   counts      = (int*)alloc((size_t)R_ * N_ * 4);
    int*   offsets     = (int*)alloc((size_t)R_ * (N_ + 1) * 4);
    int*   cursor      = (int*)alloc((size_t)R_ * N_ * 4);
    int*   srcs_sorted = (int*)alloc((size_t)R_ * E_ * 4);
    float* pe          = (float*)alloc(T_ * NH_ * 4);
    float* partials    = (float*)alloc((size_t)T_ * SEMW_BLOCKS * 2 * 4);
    float* beta2       = (float*)alloc(T_ * 2 * 4);
    float* Mu          = (float*)alloc(16384 * 4);
    float* Mwv         = (float*)alloc(16384 * 4);
    float* cbuf        = (float*)alloc(4 * 768 * 4);
    unsigned short* wt_gs0  = (unsigned short*)alloc(16384 * 2);
    unsigned short* wt_gs1  = (unsigned short*)alloc(16384 * 2);
    unsigned short* wt_gd0  = (unsigned short*)alloc(16384 * 2);
    unsigned short* wt_gd1  = (unsigned short*)alloc(16384 * 2);
    unsigned short* wt_sem  = (unsigned short*)alloc(16384 * 2);
    unsigned short* wt_res  = (unsigned short*)alloc(16384 * 2);
    unsigned short* wt_hh   = (unsigned short*)alloc(16384 * 2);
    unsigned short* wt_pu   = (unsigned short*)alloc(16384 * 2);
    unsigned short* wt_pwv  = (unsigned short*)alloc(16384 * 2);
    unsigned short* xb      = (unsigned short*)alloc((size_t)T_ * N_ * 128 * 2);   // 76.8 MB
    unsigned short* inter   = (unsigned short*)alloc((size_t)N_ * T_ * 128 * 2);   // 76.8 MB
    size_t Rgat = (size_t)4 * TB * N_ * 128 * 2;
    size_t Rtmp = (size_t)4 * CH * 6 * 128 * 2;
    unsigned short* R0      = (unsigned short*)alloc(Rgat > Rtmp ? Rgat : Rtmp);

    unsigned short* hbuf = (unsigned short*)d_out;   // TB*N*256 bf16 <= 153.6 MB; overwritten afterwards

    // --- CSR + precomputes
    hipMemsetAsync(counts, 0, (size_t)R_ * N_ * 4, stream);
    hist_kernel<<<(R_ * E_ + 255) / 256, 256, 0, stream>>>(dst, counts);
    scan_kernel<<<R_, 1024, 0, stream>>>(counts, offsets, cursor);
    scatter_kernel<<<(R_ * E_ + 255) / 256, 256, 0, stream>>>(src, dst, cursor, srcs_sorted);
    pe_kernel<<<1, 128, 0, stream>>>(pe);
    cvt_x_kernel<<<18750, 256, 0, stream>>>(x, xb, (long)T_ * N_ * 128);
    CvtArgs ca;
    ca.s[0] = gat_wsrc;         ca.d[0] = wt_gs0;
    ca.s[1] = gat_wsrc + 16384; ca.d[1] = wt_gs1;
    ca.s[2] = gat_wdst;         ca.d[2] = wt_gd0;
    ca.s[3] = gat_wdst + 16384; ca.d[3] = wt_gd1;
    ca.s[4] = sem_w1;           ca.d[4] = wt_sem;
    ca.s[5] = res_w;            ca.d[5] = wt_res;
    cvt_wt_kernel<<<dim3(128, 6), 128, 0, stream>>>(ca);
    build_m_kernel<<<dim3(128, 2), 128, 0, stream>>>(qw, kw, vw, fc_w, Mu, Mwv);
    fold_w_kernel<<<dim3(128, 3), 128, 0, stream>>>(proj_w, Mu, Mwv, wt_hh, wt_pu, wt_pwv);
    fold_c_kernel<<<6, 128, 0, stream>>>(proj_b, pe, Mu, Mwv, res_b, cbuf);

    // --- GAT phase, batched over TB timesteps per group
    size_t TBN = (size_t)TB * N_ * 128;
    for (int tg = 0; tg < T_ / TB; tg++) {
        int tbase = tg * TB;
        MArgs ga{};
        ga.A = xb + (size_t)tbase * N_ * 128;
        ga.row0 = 0; ga.M = TB * N_;
        ga.W0 = wt_gs0; ga.C0 = R0;                 // fs r0 [tl][n]
        ga.W1 = wt_gd0; ga.C1 = R0 + TBN;           // fd r0
        ga.W2 = wt_gs1; ga.C2 = R0 + 2 * TBN;       // fs r1
        ga.W3 = wt_gd1; ga.C3 = R0 + 3 * TBN;       // fd r1
        mgemm_kernel<0><<<dim3((TB * N_ + 127) / 128, 1), 256, 0, stream>>>(ga);

        gat_edge_kernel<<<dim3(1024, 2 * TB), 256, 0, stream>>>(R0, offsets, srcs_sorted,
                                                                gat_attn, gat_bias, hbuf, TB);

        semw_kernel<<<dim3(SEMW_BLOCKS, TB), 256, 0, stream>>>(hbuf, wt_sem, sem_b1, sem_w2,
                                                               partials + (size_t)tbase * SEMW_BLOCKS * 2);
        beta_kernel<<<TB, 512, 0, stream>>>(partials + (size_t)tbase * SEMW_BLOCKS * 2,
                                            beta2 + tbase * 2);
        hsem_kernel<<<dim3((N_ * 16 + 255) / 256, TB), 256, 0, stream>>>(hbuf, beta2 + tbase * 2,
                                                                         h_bias, inter, tbase);
    }

    // --- temporal attention + residual + LN (batched; overwrites d_out)
    for (int c = 0; c < N_ / CH; c++) {
        long n0 = (long)c * CH;
        long r0 = n0 * 6;
        int Mc = CH * 6;
        int nb = (Mc + 127) / 128;
        size_t MB = (size_t)Mc * 128;

        MArgs gt{};
        gt.A = inter + (size_t)r0 * 128;
        gt.Axb = xb;
        gt.row0 = r0; gt.M = Mc; gt.cb = cbuf;
        gt.W0 = wt_hh;  gt.C0 = R0;
        gt.W1 = wt_pu;  gt.C1 = R0 + MB;
        gt.W2 = wt_pwv; gt.C2 = R0 + 2 * MB;
        gt.W3 = wt_res; gt.C3 = R0 + 3 * MB;
        mgemm_kernel<3><<<dim3(nb, 1), 256, 0, stream>>>(gt);

        temporal_kernel<<<(CH + 3) / 4, 256, 0, stream>>>(R0, R0 + MB, R0 + 2 * MB, R0 + 3 * MB,
                                                          fc_b, res_alpha, ln_g, ln_b,
                                                          (float*)d_out, n0, CH);
    }
}